// Round 14
// baseline (797.254 us; speedup 1.0000x reference)
//
#include <hip/hip_runtime.h>

// ---- problem dims ----
#define SQ   2048
#define DM   768
#define NHD  12
#define DHD  64
#define FF   1536
#define NE   8
#define NL   2
#define NV   32000

typedef __attribute__((ext_vector_type(8))) short bf16x8;
typedef __attribute__((ext_vector_type(4))) float f32x4;

__device__ __forceinline__ unsigned short f2bf(float f) {
  unsigned u = __float_as_uint(f);
  return (unsigned short)((u + 0x7fffu + ((u >> 16) & 1u)) >> 16);
}
__device__ __forceinline__ float bf2f(unsigned short h) {
  return __uint_as_float(((unsigned)h) << 16);
}

// async global->LDS, 16B per lane; dest = wave-uniform base + lane*16
#define GLD16(ldsp, gp) __builtin_amdgcn_global_load_lds( \
    (const __attribute__((address_space(1))) void*)(gp),  \
    (__attribute__((address_space(3))) void*)(ldsp), 16, 0, 0)

__device__ __forceinline__ void conv8(const float* s, unsigned short* d) {
  float4 a = *(const float4*)s;
  float4 b = *(const float4*)(s + 4);
  int4 pk = make_int4(
      (int)((unsigned)f2bf(a.x) | ((unsigned)f2bf(a.y) << 16)),
      (int)((unsigned)f2bf(a.z) | ((unsigned)f2bf(a.w) << 16)),
      (int)((unsigned)f2bf(b.x) | ((unsigned)f2bf(b.y) << 16)),
      (int)((unsigned)f2bf(b.z) | ((unsigned)f2bf(b.w) << 16)));
  *(int4*)d = pk;
}

// ---------------- fp32 -> bf16 bulk convert ----------------
__global__ __launch_bounds__(256) void conv_k(const float* __restrict__ s,
    unsigned short* __restrict__ d) {
  size_t i = (size_t)(blockIdx.x * 256 + threadIdx.x) * 8;
  conv8(s + i, d + i);
}

// 3 equal regions (eg,eu,ed), contiguous dest
__global__ __launch_bounds__(256) void conv3_k(const float* __restrict__ s0,
    const float* __restrict__ s1, const float* __restrict__ s2,
    unsigned short* __restrict__ d, int per) {
  int b = blockIdx.x;
  const float* s = (b < per) ? s0 : (b < 2 * per) ? s1 : s2;
  int sb = (b < per) ? b : (b < 2 * per) ? b - per : b - 2 * per;
  size_t di = (size_t)b * 2048 + threadIdx.x * 8;
  size_t si = (size_t)sb * 2048 + threadIdx.x * 8;
  conv8(s + si, d + di);
}

// 2 regions (qw 864 blocks, ow 288), contiguous dest
__global__ __launch_bounds__(256) void conv2_k(const float* __restrict__ s0,
    const float* __restrict__ s1, unsigned short* __restrict__ d, int per0) {
  int b = blockIdx.x;
  const float* s = (b < per0) ? s0 : s1;
  int sb = (b < per0) ? b : b - per0;
  size_t di = (size_t)b * 2048 + threadIdx.x * 8;
  size_t si = (size_t)sb * 2048 + threadIdx.x * 8;
  conv8(s + si, d + di);
}

// ---------------- embedding: x = emb[tok]*sqrt(D); also zero cnt ----------
__global__ __launch_bounds__(256) void embed_k(const int* __restrict__ tok,
    const float* __restrict__ emb, float* __restrict__ x,
    unsigned short* __restrict__ xbf, int* __restrict__ cnt) {
  if (blockIdx.x == 0 && threadIdx.x < NE) cnt[threadIdx.x] = 0;
  int idx = blockIdx.x * 256 + threadIdx.x;   // < 2048*768
  int s = idx / DM, d = idx % DM;
  float v = emb[(size_t)tok[s] * DM + d] * 27.712812921102035f;
  x[idx] = v;
  xbf[idx] = f2bf(v);
}

// ============ 256x256 counted-vmcnt ring GEMM, 16 waves (logits) ============
// BM=BN=256, 1024 thr = 16 waves (4M x 4N), wave tile 64x64 -> 4 waves/SIMD.
// LDS = 4 ring slots of K=32 sub-tiles (128 KB). Phase s: {8 ds_read_b128 |
// stage(s+2): 2 GLD/thread | lgkm0 | 16 MFMA | vmcnt(2) | barrier}.
// Swizzle: LDS[r][c] = g[r][c ^ ((r>>1)&3)] (verified conflict-free).
// M%256==0, N%256==0, K%64==0. fp32 C, no bias.
__global__ __launch_bounds__(1024, 1) void gemmr_k(
    const unsigned short* __restrict__ A, long long lda,
    const unsigned short* __restrict__ B, long long ldb,
    float* __restrict__ C, long long ldc,
    int Kd, int mT)
{
  int nwg = gridDim.x, bid = blockIdx.x;
  int q = nwg >> 3, r = nwg & 7;
  int xcd = bid & 7, j = bid >> 3;
  int wid = (xcd < r ? xcd * (q + 1) : r * (q + 1) + (xcd - r) * q) + j;
  int mt = wid % mT, nt = wid / mT;     // m-fastest: B-panel reuse in XCD L2
  int m0 = mt * 256, n0 = nt * 256;

  // [slot][A=0/B=1][256 rows x 32 cols]
  __shared__ __align__(16) unsigned short lds[4][2][8192];

  int t = threadIdx.x, w = t >> 6, lane = t & 63;
  int wm = w >> 2, wn = w & 3;          // wave tile rows wm*64, cols wn*64
  int fr = lane & 15, ksg = lane >> 4;

  // staging: thread t -> row t>>2 (0..255), chunk t&3 (pre-swizzled source)
  int srow = t >> 2;
  int schunk = ((t & 3) ^ ((srow >> 1) & 3)) * 8;
  const unsigned short* sa = A + (size_t)(m0 + srow) * lda + schunk;
  const unsigned short* sb = B + (size_t)(n0 + srow) * ldb + schunk;
  int wofs = w * 512;                   // wave-uniform LDS dest (elems)

  int NS = Kd >> 5;                     // K=32 sub-tiles
  f32x4 acc[4][4] = {};

#define STAGEV(s) { \
    int sl_ = (s) & 3; \
    long long ko_ = (long long)((s) >> 1) * 64 + ((s) & 1) * 32; \
    GLD16(&lds[sl_][0][wofs], sa + ko_); \
    GLD16(&lds[sl_][1][wofs], sb + ko_); }

  // prologue: stage sub-tiles 0,1; wait s0 (s1's 2 loads may fly)
  STAGEV(0);
  STAGEV(1);
  asm volatile("s_waitcnt vmcnt(2)" ::: "memory");
  __builtin_amdgcn_s_barrier();
  __builtin_amdgcn_sched_barrier(0);

  int ko = (ksg ^ ((fr >> 1) & 3)) * 8; // swizzled read chunk (elems)
  for (int s = 0; s < NS; ++s) {
    int slot = s & 3;
    const unsigned short* Al = &lds[slot][0][0];
    const unsigned short* Bl = &lds[slot][1][0];
    bf16x8 af[4], bf[4];
    #pragma unroll
    for (int m = 0; m < 4; ++m)
      af[m] = *(const bf16x8*)&Al[(wm * 64 + m * 16 + fr) * 32 + ko];
    #pragma unroll
    for (int n = 0; n < 4; ++n)
      bf[n] = *(const bf16x8*)&Bl[(wn * 64 + n * 16 + fr) * 32 + ko];
    if (s + 2 < NS) STAGEV(s + 2);
    asm volatile("s_waitcnt lgkmcnt(0)" ::: "memory");
    __builtin_amdgcn_sched_barrier(0);
    __builtin_amdgcn_s_setprio(1);
    #pragma unroll
    for (int m = 0; m < 4; ++m)
      #pragma unroll
      for (int n = 0; n < 4; ++n)
        acc[m][n] = __builtin_amdgcn_mfma_f32_16x16x32_bf16(
            af[m], bf[n], acc[m][n], 0, 0, 0);
    __builtin_amdgcn_s_setprio(0);
    if (s + 1 < NS) {
      if (s + 2 < NS) asm volatile("s_waitcnt vmcnt(2)" ::: "memory");
      else            asm volatile("s_waitcnt vmcnt(0)" ::: "memory");
      __builtin_amdgcn_s_barrier();
      __builtin_amdgcn_sched_barrier(0);
    }
  }
#undef STAGEV

  // epilogue
  int rb = ksg * 4;
  #pragma unroll
  for (int m = 0; m < 4; ++m)
    #pragma unroll
    for (int n = 0; n < 4; ++n)
      #pragma unroll
      for (int rr = 0; rr < 4; ++rr)
        C[(size_t)(m0 + wm * 64 + m * 16 + rb + rr) * ldc +
          (n0 + wn * 64 + n * 16 + fr)] = acc[m][n][rr];
}

// ======== pipelined 128x256 GEMM engine (Z/gather; used for eg+eu) ========
template<bool GATHER, bool OBF16>
__global__ __launch_bounds__(512) void gemm256_k(
    const unsigned short* __restrict__ A, long long lda,
    const unsigned short* __restrict__ B, long long ldb, long long b_z,
    void* __restrict__ C, long long ldc, long long c_z,
    int M, int Kd, int mT, int nT, int Z, int zmod,
    const int* __restrict__ glist, long long gl_z,
    const int* __restrict__ cnt)
{
  int nwg = gridDim.x, bid = blockIdx.x;
  int q = nwg >> 3, r = nwg & 7;
  int xcd = bid & 7, j = bid >> 3;
  int wid = (xcd < r ? xcd * (q + 1) : r * (q + 1) + (xcd - r) * q) + j;
  int z = wid % Z; int rem = wid / Z;
  int mt = rem % mT, nt = rem / mT;
  int zz = z % zmod;
  int Mz = cnt ? cnt[zz] : M;
  int m0 = mt * 128, n0 = nt * 256;
  if (m0 >= Mz) return;
  (void)nT;

  const unsigned short* Bz = B + (size_t)z * b_z;

  __shared__ __align__(16) unsigned short lds[3 * 6 * 4096];

  int t = threadIdx.x, w = t >> 6, lane = t & 63;
  int wm = (w >> 2) * 64, wn = (w & 3) * 64;
  int fr = lane & 15, ksg = lane >> 4;
  int lrow = lane >> 3;
  int lchunk = ((lane & 7) ^ lrow) * 8;

  const unsigned short* sp[6];
  #pragma unroll
  for (int hh = 0; hh < 2; ++hh) {
    int gr = m0 + hh * 64 + w * 8 + lrow; if (gr >= Mz) gr = Mz - 1;
    int arow;
    if constexpr (GATHER) arow = glist[(size_t)zz * gl_z + gr]; else arow = gr;
    sp[hh] = A + (size_t)arow * lda + lchunk;
  }
  #pragma unroll
  for (int hh = 0; hh < 4; ++hh)
    sp[2 + hh] = Bz + (size_t)(n0 + hh * 64 + w * 8 + lrow) * ldb + lchunk;

  int rdA = (w >> 2) * 4096;
  int rdB = (2 + (w & 3)) * 4096;
  int stDst = w * 512;

  int rx = fr & 7;
  int off0 = (ksg ^ rx) * 8;
  int off1 = ((4 + ksg) ^ rx) * 8;

  int KT = Kd >> 6;
  f32x4 acc[4][4] = {};

  #pragma unroll
  for (int h = 0; h < 6; ++h)
    GLD16(&lds[h * 4096 + stDst], sp[h]);
  #pragma unroll
  for (int h = 0; h < 6; ++h)
    GLD16(&lds[(6 + h) * 4096 + stDst], sp[h] + 64);
  asm volatile("s_waitcnt vmcnt(6)" ::: "memory");
  __builtin_amdgcn_s_barrier();
  __builtin_amdgcn_sched_barrier(0);

  int buf = 0;
  for (int kt = 0; kt < KT; ++kt) {
    const unsigned short* Abl = &lds[buf * 6 * 4096 + rdA];
    const unsigned short* Bbl = &lds[buf * 6 * 4096 + rdB];
    int pf = (kt + 2 < KT);
    int pbuf = buf + 2; if (pbuf >= 3) pbuf -= 3;
    unsigned short* pd = &lds[pbuf * 6 * 4096 + stDst];
    long long koff = (long long)(kt + 2) * 64;

    if (pf) {
      GLD16(pd + 0 * 4096, sp[0] + koff);
      GLD16(pd + 1 * 4096, sp[1] + koff);
      GLD16(pd + 2 * 4096, sp[2] + koff);
    }
    {
      bf16x8 af[4], bv[4];
      #pragma unroll
      for (int m = 0; m < 4; ++m)
        af[m] = *(const bf16x8*)&Abl[(m * 16 + fr) * 64 + off0];
      #pragma unroll
      for (int n = 0; n < 4; ++n)
        bv[n] = *(const bf16x8*)&Bbl[(n * 16 + fr) * 64 + off0];
      __builtin_amdgcn_s_setprio(1);
      #pragma unroll
      for (int m = 0; m < 4; ++m)
        #pragma unroll
        for (int n = 0; n < 4; ++n)
          acc[m][n] = __builtin_amdgcn_mfma_f32_16x16x32_bf16(
              af[m], bv[n], acc[m][n], 0, 0, 0);
      __builtin_amdgcn_s_setprio(0);
    }
    if (pf) {
      GLD16(pd + 3 * 4096, sp[3] + koff);
      GLD16(pd + 4 * 4096, sp[4] + koff);
      GLD16(pd + 5 * 4096, sp[5] + koff);
    }
    {
      bf16x8 af[4], bv[4];
      #pragma unroll
      for (int m = 0; m < 4; ++m)
        af[m] = *(const bf16x8*)&Abl[(m * 16 + fr) * 64 + off1];
      #pragma unroll
      for (int n = 0; n < 4; ++n)
        bv[n] = *(const bf16x8*)&Bbl[(n * 16 + fr) * 64 + off1];
      __builtin_amdgcn_s_setprio(1);
      #pragma unroll
      for (int m = 0; m < 4; ++m)
        #pragma unroll
        for (int n = 0; n < 4; ++n)
          acc[m][n] = __builtin_amdgcn_mfma_f32_16x16x32_bf16(
              af[m], bv[n], acc[m][n], 0, 0, 0);
      __builtin_amdgcn_s_setprio(0);
    }
    if (pf) {
      asm volatile("s_waitcnt vmcnt(6)" ::: "memory");
    } else if (kt + 1 < KT) {
      asm volatile("s_waitcnt vmcnt(0)" ::: "memory");
    }
    __builtin_amdgcn_s_barrier();
    __builtin_amdgcn_sched_barrier(0);
    buf = buf + 1; if (buf == 3) buf = 0;
  }

  int rb = ksg * 4;
  #pragma unroll
  for (int m = 0; m < 4; ++m) {
    #pragma unroll
    for (int n = 0; n < 4; ++n) {
      #pragma unroll
      for (int rr = 0; rr < 4; ++rr) {
        int row = m0 + wm + m * 16 + rb + rr;
        if (row >= Mz) continue;
        size_t off = (size_t)z * c_z + (size_t)row * ldc +
                     (n0 + wn + n * 16 + fr);
        if constexpr (OBF16) ((unsigned short*)C)[off] = f2bf(acc[m][n][rr]);
        else                 ((float*)C)[off] = acc[m][n][rr];
      }
    }
  }
}

// ---------------- bf16 MFMA GEMM, m97 structure (+optional V-transpose) ----
template<bool GATHER, bool BIAS, bool OBF16, bool VT>
__global__ __launch_bounds__(256) void gemm_k(
    const unsigned short* __restrict__ A, long long lda, long long a_z,
    const unsigned short* __restrict__ B, long long ldb, long long b_z,
    const float* __restrict__ bias,
    void* __restrict__ C, long long ldc, long long c_z,
    int M, int N, int Kd, float scale,
    const int* __restrict__ glist, long long gl_z,
    const int* __restrict__ cnt, int mT, int nT, int Z,
    unsigned short* __restrict__ vtout)
{
  int nwg = gridDim.x, bid = blockIdx.x;
  int q = nwg >> 3, r = nwg & 7;
  int xcd = bid & 7, j = bid >> 3;
  int wid = (xcd < r ? xcd * (q + 1) : r * (q + 1) + (xcd - r) * q) + j;
  int z = wid % Z; int rem = wid / Z;
  int mt = rem % mT, nt = rem / mT;

  int Mz = cnt ? cnt[z] : M;
  int m0 = mt * 128, n0 = nt * 128;
  if (m0 >= Mz) return;

  const unsigned short* Ab = A + (size_t)z * a_z;
  const unsigned short* Bb = B + (size_t)z * b_z;

  __shared__ __align__(16) unsigned short As[128 * 64];
  __shared__ __align__(16) unsigned short Bs[128 * 64];

  int t = threadIdx.x, w = t >> 6, lane = t & 63;
  int wm = (w >> 1) * 64, wn = (w & 1) * 64;
  int fr = lane & 15, ksg = lane >> 4;
  int lrow = lane >> 3;
  int lchunk = ((lane & 7) ^ lrow) * 8;

  const unsigned short* ap[4];
  const unsigned short* bp[4];
  unsigned short* la[4];
  unsigned short* lb[4];
  #pragma unroll
  for (int i = 0; i < 4; ++i) {
    int rrow = w * 32 + i * 8 + lrow;
    int gr = m0 + rrow; if (gr >= Mz) gr = Mz - 1;
    int arow; if constexpr (GATHER) arow = glist[(size_t)z * gl_z + gr]; else arow = gr;
    ap[i] = Ab + (size_t)arow * lda + lchunk;
    int br = n0 + rrow; if (br >= N) br = N - 1;
    bp[i] = Bb + (size_t)br * ldb + lchunk;
    la[i] = &As[(w * 32 + i * 8) * 64];
    lb[i] = &Bs[(w * 32 + i * 8) * 64];
  }

  int rx = fr & 7;
  int off0 = ((0 + ksg) ^ rx) * 8;
  int off1 = ((4 + ksg) ^ rx) * 8;

  f32x4 acc[4][4] = {};

  for (int k0 = 0; k0 < Kd; k0 += 64) {
    #pragma unroll
    for (int i = 0; i < 4; ++i) GLD16(la[i], ap[i] + k0);
    #pragma unroll
    for (int i = 0; i < 4; ++i) GLD16(lb[i], bp[i] + k0);
    __syncthreads();
    #pragma unroll
    for (int kb = 0; kb < 2; ++kb) {
      int offk = kb ? off1 : off0;
      bf16x8 af[4], bv[4];
      #pragma unroll
      for (int m = 0; m < 4; ++m)
        af[m] = *(const bf16x8*)&As[(wm + m * 16 + fr) * 64 + offk];
      #pragma unroll
      for (int n = 0; n < 4; ++n)
        bv[n] = *(const bf16x8*)&Bs[(wn + n * 16 + fr) * 64 + offk];
      #pragma unroll
      for (int m = 0; m < 4; ++m)
        #pragma unroll
        for (int n = 0; n < 4; ++n)
          acc[m][n] = __builtin_amdgcn_mfma_f32_16x16x32_bf16(
              af[m], bv[n], acc[m][n], 0, 0, 0);
    }
    __syncthreads();
  }

  int rb = ksg * 4;
  #pragma unroll
  for (int m = 0; m < 4; ++m) {
    #pragma unroll
    for (int n = 0; n < 4; ++n) {
      int col = n0 + wn + n * 16 + fr;
      if (col >= N) continue;
      #pragma unroll
      for (int rr = 0; rr < 4; ++rr) {
        int row = m0 + wm + m * 16 + rb + rr;
        if (row >= Mz) continue;
        float v = acc[m][n][rr] * scale;
        if constexpr (BIAS) v += bias[col];
        size_t off = (size_t)z * c_z + (size_t)row * ldc + col;
        if constexpr (OBF16) ((unsigned short*)C)[off] = f2bf(v);
        else                 ((float*)C)[off] = v;
        if constexpr (VT) {
          if (n0 >= 2 * DM)   // whole block in V range (block-uniform)
            vtout[(size_t)(col - 2 * DM) * SQ + row] = f2bf(v);
        }
      }
    }
  }
}

// ---------------- flash attention (2-wave blocks, 32 q-rows) ----------------
__global__ __launch_bounds__(128) void flash_k(
    const unsigned short* __restrict__ qkv,   // [SQ][3*DM] bf16
    const unsigned short* __restrict__ vt,    // [NHD*DHD][SQ] bf16 (V^T)
    unsigned short* __restrict__ o)           // [SQ][DM] bf16
{
  int nwg = gridDim.x, bid = blockIdx.x;      // nwg = 768
  int cpx = nwg >> 3;
  int wid = (bid & 7) * cpx + (bid >> 3);
  int h  = wid >> 6;
  int qt = wid & 63;
  int q0 = qt * 32;

  __shared__ __align__(16) unsigned short Ks[128 * 64];
  __shared__ __align__(16) unsigned short Vs[128 * 64];
  __shared__ __align__(16) unsigned short Ps[2][16 * 136];

  int t = threadIdx.x, w = t >> 6, lane = t & 63;
  int fr = lane & 15, ksg = lane >> 4;
  int lrow = lane >> 3;
  int lchunk = ((lane & 7) ^ lrow) * 8;

  const unsigned short* qbase = qkv + (size_t)q0 * (3 * DM) + h * DHD;
  #pragma unroll
  for (int i = 0; i < 2; ++i) {
    int rrow = w * 16 + i * 8 + lrow;
    GLD16(&Ks[(w * 16 + i * 8) * 64], qbase + (size_t)rrow * (3 * DM) + lchunk);
  }
  __syncthreads();
  bf16x8 qf[2];
  {
    int row = w * 16 + fr, ph = fr & 7;
    qf[0] = *(const bf16x8*)&Ks[row * 64 + ((ksg ^ ph) * 8)];
    qf[1] = *(const bf16x8*)&Ks[row * 64 + (((4 + ksg) ^ ph) * 8)];
  }
  __syncthreads();

  const unsigned short* kbase = qkv + DM + h * DHD;
  const unsigned short* vb = vt + (size_t)(h * DHD) * SQ;

  f32x4 oacc[4] = {};
  float m_r[4] = {-1e30f, -1e30f, -1e30f, -1e30f};
  float l_r[4] = {0.f, 0.f, 0.f, 0.f};

  for (int kt = 0; kt < SQ / 128; ++kt) {
    int kk0 = kt * 128;
    #pragma unroll
    for (int i = 0; i < 8; ++i) {
      int rrow = w * 64 + i * 8 + lrow;
      GLD16(&Ks[(w * 64 + i * 8) * 64],
            kbase + (size_t)(kk0 + rrow) * (3 * DM) + lchunk);
    }
    #pragma unroll
    for (int i = 0; i < 8; ++i) {
      int p = w * 64 + i * 8 + lrow;
      GLD16(&Vs[(w * 64 + i * 8) * 64],
            vb + (size_t)(p >> 1) * SQ + kk0 + (p & 1) * 64 + lchunk);
    }
    __syncthreads();

    f32x4 sacc[8] = {};
    #pragma unroll
    for (int kb = 0; kb < 2; ++kb) {
      #pragma unroll
      for (int n = 0; n < 8; ++n) {
        int row = n * 16 + fr;
        bf16x8 bvv = *(const bf16x8*)&Ks[row * 64 +
            (((kb * 4 + ksg) ^ (fr & 7)) * 8)];
        sacc[n] = __builtin_amdgcn_mfma_f32_16x16x32_bf16(
            qf[kb], bvv, sacc[n], 0, 0, 0);
      }
    }

    #pragma unroll
    for (int r = 0; r < 4; ++r) {
      float mx = sacc[0][r];
      #pragma unroll
      for (int n = 1; n < 8; ++n) mx = fmaxf(mx, sacc[n][r]);
      mx = fmaxf(mx, __shfl_xor(mx, 1));
      mx = fmaxf(mx, __shfl_xor(mx, 2));
      mx = fmaxf(mx, __shfl_xor(mx, 4));
      mx = fmaxf(mx, __shfl_xor(mx, 8));
      float mn = fmaxf(m_r[r], mx * 0.125f);
      float resc = __expf(m_r[r] - mn);
      m_r[r] = mn;
      #pragma unroll
      for (int n = 0; n < 4; ++n) oacc[n][r] *= resc;
      float rs = 0.f;
      #pragma unroll
      for (int n = 0; n < 8; ++n) {
        float p = __expf(sacc[n][r] * 0.125f - mn);
        rs += p;
        Ps[w][(ksg * 4 + r) * 136 + n * 16 + fr] = f2bf(p);
      }
      rs += __shfl_xor(rs, 1);
      rs += __shfl_xor(rs, 2);
      rs += __shfl_xor(rs, 4);
      rs += __shfl_xor(rs, 8);
      l_r[r] = l_r[r] * resc + rs;
    }

    #pragma unroll
    for (int ksi = 0; ksi < 4; ++ksi) {
      bf16x8 pa = *(const bf16x8*)&Ps[w][fr * 136 + ksi * 32 + ksg * 8];
      #pragma unroll
      for (int n = 0; n < 4; ++n) {
        int p = (n * 16 + fr) * 2 + (ksi >> 1);
        int c = (ksi & 1) * 4 + ksg;
        bf16x8 bvv = *(const bf16x8*)&Vs[p * 64 + ((c ^ (p & 7)) * 8)];
        oacc[n] = __builtin_amdgcn_mfma_f32_16x16x32_bf16(
            pa, bvv, oacc[n], 0, 0, 0);
      }
    }
    __syncthreads();
  }

  unsigned short* ob = o + (size_t)(q0 + w * 16) * DM + h * DHD;
  #pragma unroll
  for (int r = 0; r < 4; ++r) {
    float invl = 1.f / l_r[r];
    int qrow = ksg * 4 + r;
    #pragma unroll
    for (int n = 0; n < 4; ++n)
      ob[(size_t)qrow * DM + n * 16 + fr] = f2bf(oacc[n][r] * invl);
  }
}

// ---------------- x = LN(x + add) + fused MoE gate/top-2 ----------------
__global__ __launch_bounds__(256) void add_ln_gate_k(const float* __restrict__ xin,
    const float* __restrict__ add, const float* __restrict__ w,
    const float* __restrict__ b, const float* __restrict__ gw,
    float* __restrict__ xout, unsigned short* __restrict__ xbf,
    float* __restrict__ tw, int* __restrict__ ti, int* __restrict__ cnt,
    int* __restrict__ lists, int* __restrict__ slot) {
  int row = blockIdx.x, t = threadIdx.x;
  const float* xi = xin + (size_t)row * DM;
  const float* ai = add + (size_t)row * DM;
  float v[3]; float s = 0.f, sq = 0.f;
  #pragma unroll
  for (int i = 0; i < 3; ++i) {
    int idx = t + i * 256;
    v[i] = xi[idx] + ai[idx];
    s += v[i]; sq += v[i] * v[i];
  }
  #pragma unroll
  for (int o = 32; o; o >>= 1) { s += __shfl_xor(s, o); sq += __shfl_xor(sq, o); }
  __shared__ float rsm[4], rqm[4];
  __shared__ float gsm[4][NE];
  int wv = t >> 6, lane = t & 63;
  if (lane == 0) { rsm[wv] = s; rqm[wv] = sq; }
  __syncthreads();
  s = rsm[0] + rsm[1] + rsm[2] + rsm[3];
  sq = rqm[0] + rqm[1] + rqm[2] + rqm[3];
  float mean = s * (1.f / 768.f);
  float var = sq * (1.f / 768.f) - mean * mean;
  float inv = rsqrtf(var + 1e-5f);
  float* xo = xout + (size_t)row * DM;
  unsigned short* xb = xbf + (size_t)row * DM;
  float y[3];
  #pragma unroll
  for (int i = 0; i < 3; ++i) {
    int idx = t + i * 256;
    y[i] = (v[i] - mean) * inv * w[idx] + b[idx];
    xo[idx] = y[i]; xb[idx] = f2bf(y[i]);
  }
  float p[NE];
  #pragma unroll
  for (int e = 0; e < NE; ++e) {
    p[e] = y[0] * gw[e * DM + t] + y[1] * gw[e * DM + t + 256]
         + y[2] * gw[e * DM + t + 512];
    #pragma unroll
    for (int o = 32; o; o >>= 1) p[e] += __shfl_xor(p[e], o);
  }
  if (lane == 0) {
    #pragma unroll
    for (int e = 0; e < NE; ++e) gsm[wv][e] = p[e];
  }
  __syncthreads();
  if (t == 0) {
    float v0 = -1e30f, v1 = -1e30f; int i0 = 0, i1 = 0;
    #pragma unroll
    for (int e = 0; e < NE; ++e) {
      float g = gsm[0][e] + gsm[1][e] + gsm[2][e] + gsm[3][e];
      if (g > v0) { v1 = v0; i1 = i0; v0 = g; i0 = e; }
      else if (g > v1) { v1 = g; i1 = e; }
    }
    float e1 = expf(v1 - v0);
    float invs = 1.f / (1.f + e1);
    tw[row * 2] = invs; tw[row * 2 + 1] = e1 * invs;
    ti[row * 2] = i0;   ti[row * 2 + 1] = i1;
    int p0 = atomicAdd(&cnt[i0], 1); lists[i0 * SQ + p0] = row; slot[row * 2] = p0;
    int p1 = atomicAdd(&cnt[i1], 1); lists[i1 * SQ + p1] = row; slot[row * 2 + 1] = p1;
  }
}

// ---------------- hh = silu(hg) * hu (in-place into hg) ----------------
__global__ __launch_bounds__(256) void silu_mul_k(unsigned short* __restrict__ hg,
    const unsigned short* __restrict__ hu, const int* __restrict__ cnt) {
  int e = blockIdx.y, sl = blockIdx.x;
  if (sl >= cnt[e]) return;
  size_t base = ((size_t)e * SQ + sl) * FF;
  int t = threadIdx.x;
  #pragma unroll
  for (int i = 0; i < FF / 256; ++i) {
    size_t idx = base + t + i * 256;
    float g = bf2f(hg[idx]);
    float u = bf2f(hu[idx]);
    float sv = g / (1.f + expf(-g));
    hg[idx] = f2bf(sv * u);
  }
}

// ---------------- moe combine + LN (+optional fused final RMSNorm) --------
template<bool FINAL>
__global__ __launch_bounds__(256) void combine_ln_k(const float* __restrict__ xin,
    const float* __restrict__ ye, const float* __restrict__ tw,
    const int* __restrict__ ti, const int* __restrict__ slot,
    const float* __restrict__ w, const float* __restrict__ b,
    const float* __restrict__ rw,
    float* __restrict__ xout, unsigned short* __restrict__ xbf,
    int* __restrict__ cnt) {
  int row = blockIdx.x, t = threadIdx.x;
  if (!FINAL && row < NE && t == 0) cnt[row] = 0;
  int e0 = ti[row * 2], e1 = ti[row * 2 + 1];
  int p0 = slot[row * 2], p1 = slot[row * 2 + 1];
  float w0 = tw[row * 2], w1 = tw[row * 2 + 1];
  const float* y0 = ye + ((size_t)e0 * SQ + p0) * DM;
  const float* y1 = ye + ((size_t)e1 * SQ + p1) * DM;
  const float* xi = xin + (size_t)row * DM;
  float v[3]; float s = 0.f, sq = 0.f;
  #pragma unroll
  for (int i = 0; i < 3; ++i) {
    int idx = t + i * 256;
    v[i] = xi[idx] + w0 * y0[idx] + w1 * y1[idx];
    s += v[i]; sq += v[i] * v[i];
  }
  #pragma unroll
  for (int o = 32; o; o >>= 1) { s += __shfl_xor(s, o); sq += __shfl_xor(sq, o); }
  __shared__ float rsm[4], rqm[4];
  int wv = t >> 6;
  if ((t & 63) == 0) { rsm[wv] = s; rqm[wv] = sq; }
  __syncthreads();
  s = rsm[0] + rsm[1] + rsm[2] + rsm[3];
  sq = rqm[0] + rqm[1] + rqm[2] + rqm[3];
  float mean = s * (1.f / 768.f);
  float var = sq * (1.f / 768.f) - mean * mean;
  float inv = rsqrtf(var + 1e-5f);
  unsigned short* xb = xbf + (size_t)row * DM;
  float y[3];
  #pragma unroll
  for (int i = 0; i < 3; ++i) {
    int idx = t + i * 256;
    y[i] = (v[i] - mean) * inv * w[idx] + b[idx];
  }
  if constexpr (!FINAL) {
    float* xo = xout + (size_t)row * DM;
    #pragma unroll
    for (int i = 0; i < 3; ++i) {
      int idx = t + i * 256;
      xo[idx] = y[i]; xb[idx] = f2bf(y[i]);
    }
  } else {
    float sq2 = y[0] * y[0] + y[1] * y[1] + y[2] * y[2];
    #pragma unroll
    for (int o = 32; o; o >>= 1) sq2 += __shfl_xor(sq2, o);
    __syncthreads();
    if ((t & 63) == 0) rqm[wv] = sq2;
    __syncthreads();
    sq2 = rqm[0] + rqm[1] + rqm[2] + rqm[3];
    float inv2 = rsqrtf(sq2 * (1.f / 768.f) + 1.1920929e-07f);
    #pragma unroll
    for (int i = 0; i < 3; ++i) {
      int idx = t + i * 256;
      xb[idx] = f2bf(y[i] * inv2 * rw[idx]);
    }
  }
}

// ================= host =================
extern "C" void kernel_launch(void* const* d_in, const int* in_sizes, int n_in,
                              void* d_out, int out_size, void* d_ws, size_t ws_size,
                              hipStream_t stream) {
  (void)in_sizes; (void)n_in; (void)out_size; (void)ws_size;
  const int*   tokens = (const int*)d_in[0];
  const float* emb    = (const float*)d_in[1];
  const float* qkv_w  = (const float*)d_in[2];
  const float* qkv_b  = (const float*)d_in[3];
  const float* out_w  = (const float*)d_in[4];
  const float* out_b  = (const float*)d_in[5];
  const float* ln1_w  = (const float*)d_in[6];
  const float* ln1_b  = (const float*)d_in[7];
  const float* ln2_w  = (const float*)d_in[8];
  const float* ln2_b  = (const float*)d_in[9];
  const float* gate_w = (const float*)d_in[10];
  const float* eg_w   = (const float*)d_in[11];
  const float* eu_w   = (const float*)d_in[12];
  const float* ed_w   = (const float*)d_in[13];
  const float* rms_w  = (const float*)d_in[14];
  float* out = (float*)d_out;

  char* wsb = (char*)d_ws;
  float*          x_f    = (float*)(wsb + 0);                   // 6291456
  unsigned short* x_bf   = (unsigned short*)(wsb + 6291456);    // 3145728
  unsigned short* qkv_bf = (unsigned short*)(wsb + 9437184);    // 9437184
  unsigned short* vt     = (unsigned short*)(wsb + 18874368);   // 3145728
  unsigned short* o_bf   = (unsigned short*)(wsb + 22020096);   // 3145728
  float*          tmp_f  = (float*)(wsb + 25165824);            // 6291456
  float*          tw     = (float*)(wsb + 31457280);            // 16384
  int*            ti     = (int*)(wsb + 31473664);              // 16384
  int*            cnt    = (int*)(wsb + 31490048);              // 256
  int*            lists  = (int*)(wsb + 31490304);              // 65536
  int*            slot   = (int*)(wsb + 31555840);              // 16384
  unsigned short* emb_bf = (unsigned short*)(wsb + 31572224);   // 49152000
  unsigned short* wbf    = (unsigned short*)(wsb + 80724224);   // 61341696 (one layer)
  unsigned short* hg     = (unsigned short*)(wsb + 142065920);  // 50331648
  unsigned short* hu     = (unsigned short*)(wsb + 142065920 + 50331648);
  float*          ye     = (float*)(wsb + 142065920 + 50331648); // overlaps hu

  // per-layer weight staging (producer->consumer cache locality)
  unsigned short* qw_bf = wbf;                 // 1769472
  unsigned short* ow_bf = wbf + 1769472;       // 589824
  unsigned short* eg_bf = wbf + 2359296;       // 9437184 (eu = +8*FF*DM follows)
  unsigned short* ed_bf = wbf + 21233664;      // 9437184

  conv_k<<<12000, 256, 0, stream>>>(emb, emb_bf);
  embed_k<<<SQ * DM / 256, 256, 0, stream>>>(tokens, emb, x_f, x_bf, cnt);

  for (int l = 0; l < NL; ++l) {
    const float* qw = qkv_w + (size_t)l * 3 * DM * DM;
    const float* qb = qkv_b + (size_t)l * 3 * DM;
    const float* ow = out_w + (size_t)l * DM * DM;
    const float* ob = out_b + (size_t)l * DM;
    const float* gw = gate_w + (size_t)l * NE * DM;
    const float* egw = eg_w + (size_t)l * NE * FF * DM;
    const float* euw = eu_w + (size_t)l * NE * FF * DM;
    const float* edw = ed_w + (size_t)l * NE * DM * FF;

    conv2_k<<<1152, 256, 0, stream>>>(qw, ow, qw_bf, 864);
    conv3_k<<<13824, 256, 0, stream>>>(egw, euw, edw, eg_bf, 4608);

    // qkv = x @ qkv_w^T + b -> bf16; V cols also written transposed to vt
    gemm_k<false, true, true, true><<<16 * 18, 256, 0, stream>>>(
        x_bf, DM, 0, qw_bf, DM, 0, qb, qkv_bf, 3 * DM, 0,
        SQ, 3 * DM, DM, 1.f, nullptr, 0, nullptr, 16, 18, 1, vt);

    // fused flash attention -> o_bf
    flash_k<<<NHD * 64, 128, 0, stream>>>(qkv_bf, vt, o_bf);

    // attn out-proj -> tmp_f (fp32)
    gemm_k<false, true, false, false><<<16 * 6, 256, 0, stream>>>(
        o_bf, DM, 0, ow_bf, DM, 0, ob, tmp_f, DM, 0,
        SQ, DM, DM, 1.f, nullptr, 0, nullptr, 16, 6, 1, nullptr);

    add_ln_gate_k<<<SQ, 256, 0, stream>>>(x_f, tmp_f, ln1_w + l * DM,
        ln1_b + l * DM, gw, x_f, x_bf, tw, ti, cnt, lists, slot);

    // eg + eu in ONE pipelined dispatch: Z=16 (z<8 gate, z>=8 up)
    gemm256_k<true, true><<<16 * 6 * 16, 512, 0, stream>>>(
        x_bf, DM, eg_bf, DM, (long long)FF * DM,
        hg, FF, (long long)SQ * FF,
        SQ, DM, 16, 6, 16, 8, lists, SQ, cnt);

    silu_mul_k<<<dim3(SQ, NE), 256, 0, stream>>>(hg, hu, cnt);

    // ye = hh @ ed^T (fp32 out), m97 engine: Z=8, full-chip grid
    gemm_k<false, false, false, false><<<16 * 6 * NE, 256, 0, stream>>>(
        hg, FF, (long long)SQ * FF, ed_bf, FF, (long long)DM * FF, nullptr,
        ye, DM, (long long)SQ * DM,
        SQ, DM, FF, 1.f, nullptr, 0, cnt, 16, 6, NE, nullptr);

    if (l == NL - 1)
      combine_ln_k<true><<<SQ, 256, 0, stream>>>(x_f, ye, tw, ti, slot,
          ln2_w + l * DM, ln2_b + l * DM, rms_w, x_f, x_bf, cnt);
    else
      combine_ln_k<false><<<SQ, 256, 0, stream>>>(x_f, ye, tw, ti, slot,
          ln2_w + l * DM, ln2_b + l * DM, rms_w, x_f, x_bf, cnt);
  }

  // logits = xn @ emb_bf^T (fp32) -- 16-wave counted-vmcnt ring engine
  gemmr_k<<<8 * 125, 1024, 0, stream>>>(
      x_bf, DM, emb_bf, DM, out, NV, DM, 8);
}

// Round 15
// 774.988 us; speedup vs baseline: 1.0287x; 1.0287x over previous
//
#include <hip/hip_runtime.h>

// ---- problem dims ----
#define SQ   2048
#define DM   768
#define NHD  12
#define DHD  64
#define FF   1536
#define NE   8
#define NL   2
#define NV   32000

typedef __attribute__((ext_vector_type(8))) short bf16x8;
typedef __attribute__((ext_vector_type(4))) float f32x4;

__device__ __forceinline__ unsigned short f2bf(float f) {
  unsigned u = __float_as_uint(f);
  return (unsigned short)((u + 0x7fffu + ((u >> 16) & 1u)) >> 16);
}
__device__ __forceinline__ float bf2f(unsigned short h) {
  return __uint_as_float(((unsigned)h) << 16);
}

// async global->LDS, 16B per lane; dest = wave-uniform base + lane*16
#define GLD16(ldsp, gp) __builtin_amdgcn_global_load_lds( \
    (const __attribute__((address_space(1))) void*)(gp),  \
    (__attribute__((address_space(3))) void*)(ldsp), 16, 0, 0)

__device__ __forceinline__ void conv8(const float* s, unsigned short* d) {
  float4 a = *(const float4*)s;
  float4 b = *(const float4*)(s + 4);
  int4 pk = make_int4(
      (int)((unsigned)f2bf(a.x) | ((unsigned)f2bf(a.y) << 16)),
      (int)((unsigned)f2bf(a.z) | ((unsigned)f2bf(a.w) << 16)),
      (int)((unsigned)f2bf(b.x) | ((unsigned)f2bf(b.y) << 16)),
      (int)((unsigned)f2bf(b.z) | ((unsigned)f2bf(b.w) << 16)));
  *(int4*)d = pk;
}

// ---------------- fp32 -> bf16 bulk convert ----------------
__global__ __launch_bounds__(256) void conv_k(const float* __restrict__ s,
    unsigned short* __restrict__ d) {
  size_t i = (size_t)(blockIdx.x * 256 + threadIdx.x) * 8;
  conv8(s + i, d + i);
}

// 5 regions (qw 864, ow 288, eg 4608, eu 4608, ed 4608), contiguous dest
__global__ __launch_bounds__(256) void conv5_k(const float* __restrict__ s0,
    const float* __restrict__ s1, const float* __restrict__ s2,
    const float* __restrict__ s3, const float* __restrict__ s4,
    unsigned short* __restrict__ d) {
  int b = blockIdx.x;
  const float* s; int sb;
  if (b < 864)        { s = s0; sb = b; }
  else if (b < 1152)  { s = s1; sb = b - 864; }
  else if (b < 5760)  { s = s2; sb = b - 1152; }
  else if (b < 10368) { s = s3; sb = b - 5760; }
  else                { s = s4; sb = b - 10368; }
  size_t di = (size_t)b * 2048 + threadIdx.x * 8;
  size_t si = (size_t)sb * 2048 + threadIdx.x * 8;
  conv8(s + si, d + di);
}

// ---------------- embedding: x = emb[tok]*sqrt(D); also zero cnt ----------
__global__ __launch_bounds__(256) void embed_k(const int* __restrict__ tok,
    const float* __restrict__ emb, float* __restrict__ x,
    unsigned short* __restrict__ xbf, int* __restrict__ cnt) {
  if (blockIdx.x == 0 && threadIdx.x < NE) cnt[threadIdx.x] = 0;
  int idx = blockIdx.x * 256 + threadIdx.x;   // < 2048*768
  int s = idx / DM, d = idx % DM;
  float v = emb[(size_t)tok[s] * DM + d] * 27.712812921102035f;
  x[idx] = v;
  xbf[idx] = f2bf(v);
}

// ============ 256x256 counted-vmcnt ring GEMM (logits engine) ============
// BM=BN=256, 512 thr = 8 waves (2M x 4N), wave tile 128x64.
// LDS = 4 ring slots of K=32 sub-tiles (128 KB). Phase s: {12 ds_read(s) |
// stage(s+2): 4 GLD | lgkm0 | 32 MFMA | vmcnt(4) | barrier}. Swizzle:
// LDS[r][c] = g[r][c ^ ((r>>1)&3)] -> conflict-free b128 lane groups.
__global__ __launch_bounds__(512, 1) void gemmr_k(
    const unsigned short* __restrict__ A, long long lda,
    const unsigned short* __restrict__ B, long long ldb,
    float* __restrict__ C, long long ldc,
    int Kd, int mT)
{
  int nwg = gridDim.x, bid = blockIdx.x;
  int q = nwg >> 3, r = nwg & 7;
  int xcd = bid & 7, j = bid >> 3;
  int wid = (xcd < r ? xcd * (q + 1) : r * (q + 1) + (xcd - r) * q) + j;
  int mt = wid % mT, nt = wid / mT;     // m-fastest: B-panel reuse in XCD L2
  int m0 = mt * 256, n0 = nt * 256;

  __shared__ __align__(16) unsigned short lds[4][2][8192];

  int t = threadIdx.x, w = t >> 6, lane = t & 63;
  int wm = w >> 2, wn = w & 3;
  int fr = lane & 15, ksg = lane >> 4;

  int srow = t >> 2;                    // 0..127
  int schunk = ((t & 3) ^ ((srow >> 1) & 3)) * 8;
  const unsigned short* sa0 = A + (size_t)(m0 +       srow) * lda + schunk;
  const unsigned short* sa1 = A + (size_t)(m0 + 128 + srow) * lda + schunk;
  const unsigned short* sb0 = B + (size_t)(n0 +       srow) * ldb + schunk;
  const unsigned short* sb1 = B + (size_t)(n0 + 128 + srow) * ldb + schunk;
  int wofs = w * 512;

  int NS = Kd >> 5;
  f32x4 acc[8][4] = {};

#define STAGEV(s) { \
    int sl_ = (s) & 3; \
    long long ko_ = (long long)((s) >> 1) * 64 + ((s) & 1) * 32; \
    GLD16(&lds[sl_][0][wofs], sa0 + ko_); \
    GLD16(&lds[sl_][0][4096 + wofs], sa1 + ko_); \
    GLD16(&lds[sl_][1][wofs], sb0 + ko_); \
    GLD16(&lds[sl_][1][4096 + wofs], sb1 + ko_); }

  STAGEV(0);
  STAGEV(1);
  asm volatile("s_waitcnt vmcnt(4)" ::: "memory");
  __builtin_amdgcn_s_barrier();
  __builtin_amdgcn_sched_barrier(0);

  int ko = (ksg ^ ((fr >> 1) & 3)) * 8;
  for (int s = 0; s < NS; ++s) {
    int slot = s & 3;
    const unsigned short* Al = &lds[slot][0][0];
    const unsigned short* Bl = &lds[slot][1][0];
    bf16x8 af[8], bf[4];
    #pragma unroll
    for (int m = 0; m < 8; ++m)
      af[m] = *(const bf16x8*)&Al[(wm * 128 + m * 16 + fr) * 32 + ko];
    #pragma unroll
    for (int n = 0; n < 4; ++n)
      bf[n] = *(const bf16x8*)&Bl[(wn * 64 + n * 16 + fr) * 32 + ko];
    if (s + 2 < NS) STAGEV(s + 2);
    asm volatile("s_waitcnt lgkmcnt(0)" ::: "memory");
    __builtin_amdgcn_sched_barrier(0);
    __builtin_amdgcn_s_setprio(1);
    #pragma unroll
    for (int m = 0; m < 8; ++m)
      #pragma unroll
      for (int n = 0; n < 4; ++n)
        acc[m][n] = __builtin_amdgcn_mfma_f32_16x16x32_bf16(
            af[m], bf[n], acc[m][n], 0, 0, 0);
    __builtin_amdgcn_s_setprio(0);
    if (s + 1 < NS) {
      if (s + 2 < NS) asm volatile("s_waitcnt vmcnt(4)" ::: "memory");
      else            asm volatile("s_waitcnt vmcnt(0)" ::: "memory");
      __builtin_amdgcn_s_barrier();
      __builtin_amdgcn_sched_barrier(0);
    }
  }
#undef STAGEV

  int rb = ksg * 4;
  #pragma unroll
  for (int M = 0; M < 8; ++M)
    #pragma unroll
    for (int n = 0; n < 4; ++n)
      #pragma unroll
      for (int rr = 0; rr < 4; ++rr)
        C[(size_t)(m0 + wm * 128 + M * 16 + rb + rr) * ldc +
          (n0 + wn * 64 + n * 16 + fr)] = acc[M][n][rr];
}

// ======== pipelined 128x256 GEMM engine (Z/gather; used for eg+eu) ========
template<bool GATHER, bool OBF16>
__global__ __launch_bounds__(512) void gemm256_k(
    const unsigned short* __restrict__ A, long long lda,
    const unsigned short* __restrict__ B, long long ldb, long long b_z,
    void* __restrict__ C, long long ldc, long long c_z,
    int M, int Kd, int mT, int nT, int Z, int zmod,
    const int* __restrict__ glist, long long gl_z,
    const int* __restrict__ cnt)
{
  int nwg = gridDim.x, bid = blockIdx.x;
  int q = nwg >> 3, r = nwg & 7;
  int xcd = bid & 7, j = bid >> 3;
  int wid = (xcd < r ? xcd * (q + 1) : r * (q + 1) + (xcd - r) * q) + j;
  int z = wid % Z; int rem = wid / Z;
  int mt = rem % mT, nt = rem / mT;
  int zz = z % zmod;
  int Mz = cnt ? cnt[zz] : M;
  int m0 = mt * 128, n0 = nt * 256;
  if (m0 >= Mz) return;
  (void)nT;

  const unsigned short* Bz = B + (size_t)z * b_z;

  __shared__ __align__(16) unsigned short lds[3 * 6 * 4096];

  int t = threadIdx.x, w = t >> 6, lane = t & 63;
  int wm = (w >> 2) * 64, wn = (w & 3) * 64;
  int fr = lane & 15, ksg = lane >> 4;
  int lrow = lane >> 3;
  int lchunk = ((lane & 7) ^ lrow) * 8;

  const unsigned short* sp[6];
  #pragma unroll
  for (int hh = 0; hh < 2; ++hh) {
    int gr = m0 + hh * 64 + w * 8 + lrow; if (gr >= Mz) gr = Mz - 1;
    int arow;
    if constexpr (GATHER) arow = glist[(size_t)zz * gl_z + gr]; else arow = gr;
    sp[hh] = A + (size_t)arow * lda + lchunk;
  }
  #pragma unroll
  for (int hh = 0; hh < 4; ++hh)
    sp[2 + hh] = Bz + (size_t)(n0 + hh * 64 + w * 8 + lrow) * ldb + lchunk;

  int rdA = (w >> 2) * 4096;
  int rdB = (2 + (w & 3)) * 4096;
  int stDst = w * 512;

  int rx = fr & 7;
  int off0 = (ksg ^ rx) * 8;
  int off1 = ((4 + ksg) ^ rx) * 8;

  int KT = Kd >> 6;
  f32x4 acc[4][4] = {};

  #pragma unroll
  for (int h = 0; h < 6; ++h)
    GLD16(&lds[h * 4096 + stDst], sp[h]);
  #pragma unroll
  for (int h = 0; h < 6; ++h)
    GLD16(&lds[(6 + h) * 4096 + stDst], sp[h] + 64);
  asm volatile("s_waitcnt vmcnt(6)" ::: "memory");
  __builtin_amdgcn_s_barrier();
  __builtin_amdgcn_sched_barrier(0);

  int buf = 0;
  for (int kt = 0; kt < KT; ++kt) {
    const unsigned short* Abl = &lds[buf * 6 * 4096 + rdA];
    const unsigned short* Bbl = &lds[buf * 6 * 4096 + rdB];
    int pf = (kt + 2 < KT);
    int pbuf = buf + 2; if (pbuf >= 3) pbuf -= 3;
    unsigned short* pd = &lds[pbuf * 6 * 4096 + stDst];
    long long koff = (long long)(kt + 2) * 64;

    if (pf) {
      GLD16(pd + 0 * 4096, sp[0] + koff);
      GLD16(pd + 1 * 4096, sp[1] + koff);
      GLD16(pd + 2 * 4096, sp[2] + koff);
    }
    {
      bf16x8 af[4], bv[4];
      #pragma unroll
      for (int m = 0; m < 4; ++m)
        af[m] = *(const bf16x8*)&Abl[(m * 16 + fr) * 64 + off0];
      #pragma unroll
      for (int n = 0; n < 4; ++n)
        bv[n] = *(const bf16x8*)&Bbl[(n * 16 + fr) * 64 + off0];
      __builtin_amdgcn_s_setprio(1);
      #pragma unroll
      for (int m = 0; m < 4; ++m)
        #pragma unroll
        for (int n = 0; n < 4; ++n)
          acc[m][n] = __builtin_amdgcn_mfma_f32_16x16x32_bf16(
              af[m], bv[n], acc[m][n], 0, 0, 0);
      __builtin_amdgcn_s_setprio(0);
    }
    if (pf) {
      GLD16(pd + 3 * 4096, sp[3] + koff);
      GLD16(pd + 4 * 4096, sp[4] + koff);
      GLD16(pd + 5 * 4096, sp[5] + koff);
    }
    {
      bf16x8 af[4], bv[4];
      #pragma unroll
      for (int m = 0; m < 4; ++m)
        af[m] = *(const bf16x8*)&Abl[(m * 16 + fr) * 64 + off1];
      #pragma unroll
      for (int n = 0; n < 4; ++n)
        bv[n] = *(const bf16x8*)&Bbl[(n * 16 + fr) * 64 + off1];
      __builtin_amdgcn_s_setprio(1);
      #pragma unroll
      for (int m = 0; m < 4; ++m)
        #pragma unroll
        for (int n = 0; n < 4; ++n)
          acc[m][n] = __builtin_amdgcn_mfma_f32_16x16x32_bf16(
              af[m], bv[n], acc[m][n], 0, 0, 0);
      __builtin_amdgcn_s_setprio(0);
    }
    if (pf) {
      asm volatile("s_waitcnt vmcnt(6)" ::: "memory");
    } else if (kt + 1 < KT) {
      asm volatile("s_waitcnt vmcnt(0)" ::: "memory");
    }
    __builtin_amdgcn_s_barrier();
    __builtin_amdgcn_sched_barrier(0);
    buf = buf + 1; if (buf == 3) buf = 0;
  }

  int rb = ksg * 4;
  #pragma unroll
  for (int m = 0; m < 4; ++m) {
    #pragma unroll
    for (int n = 0; n < 4; ++n) {
      #pragma unroll
      for (int rr = 0; rr < 4; ++rr) {
        int row = m0 + wm + m * 16 + rb + rr;
        if (row >= Mz) continue;
        size_t off = (size_t)z * c_z + (size_t)row * ldc +
                     (n0 + wn + n * 16 + fr);
        if constexpr (OBF16) ((unsigned short*)C)[off] = f2bf(acc[m][n][rr]);
        else                 ((float*)C)[off] = acc[m][n][rr];
      }
    }
  }
}

// ---------------- bf16 MFMA GEMM, m97 structure (+optional V-transpose) ----
template<bool GATHER, bool BIAS, bool OBF16, bool VT>
__global__ __launch_bounds__(256) void gemm_k(
    const unsigned short* __restrict__ A, long long lda, long long a_z,
    const unsigned short* __restrict__ B, long long ldb, long long b_z,
    const float* __restrict__ bias,
    void* __restrict__ C, long long ldc, long long c_z,
    int M, int N, int Kd, float scale,
    const int* __restrict__ glist, long long gl_z,
    const int* __restrict__ cnt, int mT, int nT, int Z,
    unsigned short* __restrict__ vtout)
{
  int nwg = gridDim.x, bid = blockIdx.x;
  int q = nwg >> 3, r = nwg & 7;
  int xcd = bid & 7, j = bid >> 3;
  int wid = (xcd < r ? xcd * (q + 1) : r * (q + 1) + (xcd - r) * q) + j;
  int z = wid % Z; int rem = wid / Z;
  int mt = rem % mT, nt = rem / mT;

  int Mz = cnt ? cnt[z] : M;
  int m0 = mt * 128, n0 = nt * 128;
  if (m0 >= Mz) return;

  const unsigned short* Ab = A + (size_t)z * a_z;
  const unsigned short* Bb = B + (size_t)z * b_z;

  __shared__ __align__(16) unsigned short As[128 * 64];
  __shared__ __align__(16) unsigned short Bs[128 * 64];

  int t = threadIdx.x, w = t >> 6, lane = t & 63;
  int wm = (w >> 1) * 64, wn = (w & 1) * 64;
  int fr = lane & 15, ksg = lane >> 4;
  int lrow = lane >> 3;
  int lchunk = ((lane & 7) ^ lrow) * 8;

  const unsigned short* ap[4];
  const unsigned short* bp[4];
  unsigned short* la[4];
  unsigned short* lb[4];
  #pragma unroll
  for (int i = 0; i < 4; ++i) {
    int rrow = w * 32 + i * 8 + lrow;
    int gr = m0 + rrow; if (gr >= Mz) gr = Mz - 1;
    int arow; if constexpr (GATHER) arow = glist[(size_t)z * gl_z + gr]; else arow = gr;
    ap[i] = Ab + (size_t)arow * lda + lchunk;
    int br = n0 + rrow; if (br >= N) br = N - 1;
    bp[i] = Bb + (size_t)br * ldb + lchunk;
    la[i] = &As[(w * 32 + i * 8) * 64];
    lb[i] = &Bs[(w * 32 + i * 8) * 64];
  }

  int rx = fr & 7;
  int off0 = ((0 + ksg) ^ rx) * 8;
  int off1 = ((4 + ksg) ^ rx) * 8;

  f32x4 acc[4][4] = {};

  for (int k0 = 0; k0 < Kd; k0 += 64) {
    #pragma unroll
    for (int i = 0; i < 4; ++i) GLD16(la[i], ap[i] + k0);
    #pragma unroll
    for (int i = 0; i < 4; ++i) GLD16(lb[i], bp[i] + k0);
    __syncthreads();
    #pragma unroll
    for (int kb = 0; kb < 2; ++kb) {
      int offk = kb ? off1 : off0;
      bf16x8 af[4], bv[4];
      #pragma unroll
      for (int m = 0; m < 4; ++m)
        af[m] = *(const bf16x8*)&As[(wm + m * 16 + fr) * 64 + offk];
      #pragma unroll
      for (int n = 0; n < 4; ++n)
        bv[n] = *(const bf16x8*)&Bs[(wn + n * 16 + fr) * 64 + offk];
      #pragma unroll
      for (int m = 0; m < 4; ++m)
        #pragma unroll
        for (int n = 0; n < 4; ++n)
          acc[m][n] = __builtin_amdgcn_mfma_f32_16x16x32_bf16(
              af[m], bv[n], acc[m][n], 0, 0, 0);
    }
    __syncthreads();
  }

  int rb = ksg * 4;
  #pragma unroll
  for (int m = 0; m < 4; ++m) {
    #pragma unroll
    for (int n = 0; n < 4; ++n) {
      int col = n0 + wn + n * 16 + fr;
      if (col >= N) continue;
      #pragma unroll
      for (int rr = 0; rr < 4; ++rr) {
        int row = m0 + wm + m * 16 + rb + rr;
        if (row >= Mz) continue;
        float v = acc[m][n][rr] * scale;
        if constexpr (BIAS) v += bias[col];
        size_t off = (size_t)z * c_z + (size_t)row * ldc + col;
        if constexpr (OBF16) ((unsigned short*)C)[off] = f2bf(v);
        else                 ((float*)C)[off] = v;
        if constexpr (VT) {
          if (n0 >= 2 * DM)   // whole block in V range (block-uniform)
            vtout[(size_t)(col - 2 * DM) * SQ + row] = f2bf(v);
        }
      }
    }
  }
}

// ---------------- flash attention (2-wave blocks, 32 q-rows) ----------------
__global__ __launch_bounds__(128) void flash_k(
    const unsigned short* __restrict__ qkv,   // [SQ][3*DM] bf16
    const unsigned short* __restrict__ vt,    // [NHD*DHD][SQ] bf16 (V^T)
    unsigned short* __restrict__ o)           // [SQ][DM] bf16
{
  int nwg = gridDim.x, bid = blockIdx.x;      // nwg = 768
  int cpx = nwg >> 3;
  int wid = (bid & 7) * cpx + (bid >> 3);
  int h  = wid >> 6;
  int qt = wid & 63;
  int q0 = qt * 32;

  __shared__ __align__(16) unsigned short Ks[128 * 64];
  __shared__ __align__(16) unsigned short Vs[128 * 64];
  __shared__ __align__(16) unsigned short Ps[2][16 * 136];

  int t = threadIdx.x, w = t >> 6, lane = t & 63;
  int fr = lane & 15, ksg = lane >> 4;
  int lrow = lane >> 3;
  int lchunk = ((lane & 7) ^ lrow) * 8;

  const unsigned short* qbase = qkv + (size_t)q0 * (3 * DM) + h * DHD;
  #pragma unroll
  for (int i = 0; i < 2; ++i) {
    int rrow = w * 16 + i * 8 + lrow;
    GLD16(&Ks[(w * 16 + i * 8) * 64], qbase + (size_t)rrow * (3 * DM) + lchunk);
  }
  __syncthreads();
  bf16x8 qf[2];
  {
    int row = w * 16 + fr, ph = fr & 7;
    qf[0] = *(const bf16x8*)&Ks[row * 64 + ((ksg ^ ph) * 8)];
    qf[1] = *(const bf16x8*)&Ks[row * 64 + (((4 + ksg) ^ ph) * 8)];
  }
  __syncthreads();

  const unsigned short* kbase = qkv + DM + h * DHD;
  const unsigned short* vb = vt + (size_t)(h * DHD) * SQ;

  f32x4 oacc[4] = {};
  float m_r[4] = {-1e30f, -1e30f, -1e30f, -1e30f};
  float l_r[4] = {0.f, 0.f, 0.f, 0.f};

  for (int kt = 0; kt < SQ / 128; ++kt) {
    int kk0 = kt * 128;
    #pragma unroll
    for (int i = 0; i < 8; ++i) {
      int rrow = w * 64 + i * 8 + lrow;
      GLD16(&Ks[(w * 64 + i * 8) * 64],
            kbase + (size_t)(kk0 + rrow) * (3 * DM) + lchunk);
    }
    #pragma unroll
    for (int i = 0; i < 8; ++i) {
      int p = w * 64 + i * 8 + lrow;
      GLD16(&Vs[(w * 64 + i * 8) * 64],
            vb + (size_t)(p >> 1) * SQ + kk0 + (p & 1) * 64 + lchunk);
    }
    __syncthreads();

    f32x4 sacc[8] = {};
    #pragma unroll
    for (int kb = 0; kb < 2; ++kb) {
      #pragma unroll
      for (int n = 0; n < 8; ++n) {
        int row = n * 16 + fr;
        bf16x8 bvv = *(const bf16x8*)&Ks[row * 64 +
            (((kb * 4 + ksg) ^ (fr & 7)) * 8)];
        sacc[n] = __builtin_amdgcn_mfma_f32_16x16x32_bf16(
            qf[kb], bvv, sacc[n], 0, 0, 0);
      }
    }

    #pragma unroll
    for (int r = 0; r < 4; ++r) {
      float mx = sacc[0][r];
      #pragma unroll
      for (int n = 1; n < 8; ++n) mx = fmaxf(mx, sacc[n][r]);
      mx = fmaxf(mx, __shfl_xor(mx, 1));
      mx = fmaxf(mx, __shfl_xor(mx, 2));
      mx = fmaxf(mx, __shfl_xor(mx, 4));
      mx = fmaxf(mx, __shfl_xor(mx, 8));
      float mn = fmaxf(m_r[r], mx * 0.125f);
      float resc = __expf(m_r[r] - mn);
      m_r[r] = mn;
      #pragma unroll
      for (int n = 0; n < 4; ++n) oacc[n][r] *= resc;
      float rs = 0.f;
      #pragma unroll
      for (int n = 0; n < 8; ++n) {
        float p = __expf(sacc[n][r] * 0.125f - mn);
        rs += p;
        Ps[w][(ksg * 4 + r) * 136 + n * 16 + fr] = f2bf(p);
      }
      rs += __shfl_xor(rs, 1);
      rs += __shfl_xor(rs, 2);
      rs += __shfl_xor(rs, 4);
      rs += __shfl_xor(rs, 8);
      l_r[r] = l_r[r] * resc + rs;
    }

    #pragma unroll
    for (int ksi = 0; ksi < 4; ++ksi) {
      bf16x8 pa = *(const bf16x8*)&Ps[w][fr * 136 + ksi * 32 + ksg * 8];
      #pragma unroll
      for (int n = 0; n < 4; ++n) {
        int p = (n * 16 + fr) * 2 + (ksi >> 1);
        int c = (ksi & 1) * 4 + ksg;
        bf16x8 bvv = *(const bf16x8*)&Vs[p * 64 + ((c ^ (p & 7)) * 8)];
        oacc[n] = __builtin_amdgcn_mfma_f32_16x16x32_bf16(
            pa, bvv, oacc[n], 0, 0, 0);
      }
    }
    __syncthreads();
  }

  unsigned short* ob = o + (size_t)(q0 + w * 16) * DM + h * DHD;
  #pragma unroll
  for (int r = 0; r < 4; ++r) {
    float invl = 1.f / l_r[r];
    int qrow = ksg * 4 + r;
    #pragma unroll
    for (int n = 0; n < 4; ++n)
      ob[(size_t)qrow * DM + n * 16 + fr] = f2bf(oacc[n][r] * invl);
  }
}

// ---------------- x = LN(x + add) + fused MoE gate/top-2 ----------------
__global__ __launch_bounds__(256) void add_ln_gate_k(const float* __restrict__ xin,
    const float* __restrict__ add, const float* __restrict__ w,
    const float* __restrict__ b, const float* __restrict__ gw,
    float* __restrict__ xout, unsigned short* __restrict__ xbf,
    float* __restrict__ tw, int* __restrict__ ti, int* __restrict__ cnt,
    int* __restrict__ lists, int* __restrict__ slot) {
  int row = blockIdx.x, t = threadIdx.x;
  const float* xi = xin + (size_t)row * DM;
  const float* ai = add + (size_t)row * DM;
  float v[3]; float s = 0.f, sq = 0.f;
  #pragma unroll
  for (int i = 0; i < 3; ++i) {
    int idx = t + i * 256;
    v[i] = xi[idx] + ai[idx];
    s += v[i]; sq += v[i] * v[i];
  }
  #pragma unroll
  for (int o = 32; o; o >>= 1) { s += __shfl_xor(s, o); sq += __shfl_xor(sq, o); }
  __shared__ float rsm[4], rqm[4];
  __shared__ float gsm[4][NE];
  int wv = t >> 6, lane = t & 63;
  if (lane == 0) { rsm[wv] = s; rqm[wv] = sq; }
  __syncthreads();
  s = rsm[0] + rsm[1] + rsm[2] + rsm[3];
  sq = rqm[0] + rqm[1] + rqm[2] + rqm[3];
  float mean = s * (1.f / 768.f);
  float var = sq * (1.f / 768.f) - mean * mean;
  float inv = rsqrtf(var + 1e-5f);
  float* xo = xout + (size_t)row * DM;
  unsigned short* xb = xbf + (size_t)row * DM;
  float y[3];
  #pragma unroll
  for (int i = 0; i < 3; ++i) {
    int idx = t + i * 256;
    y[i] = (v[i] - mean) * inv * w[idx] + b[idx];
    xo[idx] = y[i]; xb[idx] = f2bf(y[i]);
  }
  float p[NE];
  #pragma unroll
  for (int e = 0; e < NE; ++e) {
    p[e] = y[0] * gw[e * DM + t] + y[1] * gw[e * DM + t + 256]
         + y[2] * gw[e * DM + t + 512];
    #pragma unroll
    for (int o = 32; o; o >>= 1) p[e] += __shfl_xor(p[e], o);
  }
  if (lane == 0) {
    #pragma unroll
    for (int e = 0; e < NE; ++e) gsm[wv][e] = p[e];
  }
  __syncthreads();
  if (t == 0) {
    float v0 = -1e30f, v1 = -1e30f; int i0 = 0, i1 = 0;
    #pragma unroll
    for (int e = 0; e < NE; ++e) {
      float g = gsm[0][e] + gsm[1][e] + gsm[2][e] + gsm[3][e];
      if (g > v0) { v1 = v0; i1 = i0; v0 = g; i0 = e; }
      else if (g > v1) { v1 = g; i1 = e; }
    }
    float e1 = expf(v1 - v0);
    float invs = 1.f / (1.f + e1);
    tw[row * 2] = invs; tw[row * 2 + 1] = e1 * invs;
    ti[row * 2] = i0;   ti[row * 2 + 1] = i1;
    int p0 = atomicAdd(&cnt[i0], 1); lists[i0 * SQ + p0] = row; slot[row * 2] = p0;
    int p1 = atomicAdd(&cnt[i1], 1); lists[i1 * SQ + p1] = row; slot[row * 2 + 1] = p1;
  }
}

// ---------------- hh = silu(hg) * hu (in-place into hg) ----------------
__global__ __launch_bounds__(256) void silu_mul_k(unsigned short* __restrict__ hg,
    const unsigned short* __restrict__ hu, const int* __restrict__ cnt) {
  int e = blockIdx.y, sl = blockIdx.x;
  if (sl >= cnt[e]) return;
  size_t base = ((size_t)e * SQ + sl) * FF;
  int t = threadIdx.x;
  #pragma unroll
  for (int i = 0; i < FF / 256; ++i) {
    size_t idx = base + t + i * 256;
    float g = bf2f(hg[idx]);
    float u = bf2f(hu[idx]);
    float sv = g / (1.f + expf(-g));
    hg[idx] = f2bf(sv * u);
  }
}

// ---------------- moe combine + LN (+optional fused final RMSNorm) --------
template<bool FINAL>
__global__ __launch_bounds__(256) void combine_ln_k(const float* __restrict__ xin,
    const float* __restrict__ ye, const float* __restrict__ tw,
    const int* __restrict__ ti, const int* __restrict__ slot,
    const float* __restrict__ w, const float* __restrict__ b,
    const float* __restrict__ rw,
    float* __restrict__ xout, unsigned short* __restrict__ xbf,
    int* __restrict__ cnt) {
  int row = blockIdx.x, t = threadIdx.x;
  if (!FINAL && row < NE && t == 0) cnt[row] = 0;
  int e0 = ti[row * 2], e1 = ti[row * 2 + 1];
  int p0 = slot[row * 2], p1 = slot[row * 2 + 1];
  float w0 = tw[row * 2], w1 = tw[row * 2 + 1];
  const float* y0 = ye + ((size_t)e0 * SQ + p0) * DM;
  const float* y1 = ye + ((size_t)e1 * SQ + p1) * DM;
  const float* xi = xin + (size_t)row * DM;
  float v[3]; float s = 0.f, sq = 0.f;
  #pragma unroll
  for (int i = 0; i < 3; ++i) {
    int idx = t + i * 256;
    v[i] = xi[idx] + w0 * y0[idx] + w1 * y1[idx];
    s += v[i]; sq += v[i] * v[i];
  }
  #pragma unroll
  for (int o = 32; o; o >>= 1) { s += __shfl_xor(s, o); sq += __shfl_xor(sq, o); }
  __shared__ float rsm[4], rqm[4];
  int wv = t >> 6;
  if ((t & 63) == 0) { rsm[wv] = s; rqm[wv] = sq; }
  __syncthreads();
  s = rsm[0] + rsm[1] + rsm[2] + rsm[3];
  sq = rqm[0] + rqm[1] + rqm[2] + rqm[3];
  float mean = s * (1.f / 768.f);
  float var = sq * (1.f / 768.f) - mean * mean;
  float inv = rsqrtf(var + 1e-5f);
  unsigned short* xb = xbf + (size_t)row * DM;
  float y[3];
  #pragma unroll
  for (int i = 0; i < 3; ++i) {
    int idx = t + i * 256;
    y[i] = (v[i] - mean) * inv * w[idx] + b[idx];
  }
  if constexpr (!FINAL) {
    float* xo = xout + (size_t)row * DM;
    #pragma unroll
    for (int i = 0; i < 3; ++i) {
      int idx = t + i * 256;
      xo[idx] = y[i]; xb[idx] = f2bf(y[i]);
    }
  } else {
    float sq2 = y[0] * y[0] + y[1] * y[1] + y[2] * y[2];
    #pragma unroll
    for (int o = 32; o; o >>= 1) sq2 += __shfl_xor(sq2, o);
    __syncthreads();
    if ((t & 63) == 0) rqm[wv] = sq2;
    __syncthreads();
    sq2 = rqm[0] + rqm[1] + rqm[2] + rqm[3];
    float inv2 = rsqrtf(sq2 * (1.f / 768.f) + 1.1920929e-07f);
    #pragma unroll
    for (int i = 0; i < 3; ++i) {
      int idx = t + i * 256;
      xb[idx] = f2bf(y[i] * inv2 * rw[idx]);
    }
  }
}

// ================= host =================
extern "C" void kernel_launch(void* const* d_in, const int* in_sizes, int n_in,
                              void* d_out, int out_size, void* d_ws, size_t ws_size,
                              hipStream_t stream) {
  (void)in_sizes; (void)n_in; (void)out_size; (void)ws_size;
  const int*   tokens = (const int*)d_in[0];
  const float* emb    = (const float*)d_in[1];
  const float* qkv_w  = (const float*)d_in[2];
  const float* qkv_b  = (const float*)d_in[3];
  const float* out_w  = (const float*)d_in[4];
  const float* out_b  = (const float*)d_in[5];
  const float* ln1_w  = (const float*)d_in[6];
  const float* ln1_b  = (const float*)d_in[7];
  const float* ln2_w  = (const float*)d_in[8];
  const float* ln2_b  = (const float*)d_in[9];
  const float* gate_w = (const float*)d_in[10];
  const float* eg_w   = (const float*)d_in[11];
  const float* eu_w   = (const float*)d_in[12];
  const float* ed_w   = (const float*)d_in[13];
  const float* rms_w  = (const float*)d_in[14];
  float* out = (float*)d_out;

  char* wsb = (char*)d_ws;
  float*          x_f    = (float*)(wsb + 0);                   // 6291456
  unsigned short* x_bf   = (unsigned short*)(wsb + 6291456);    // 3145728
  unsigned short* qkv_bf = (unsigned short*)(wsb + 9437184);    // 9437184
  unsigned short* vt     = (unsigned short*)(wsb + 18874368);   // 3145728
  unsigned short* o_bf   = (unsigned short*)(wsb + 22020096);   // 3145728
  float*          tmp_f  = (float*)(wsb + 25165824);            // 6291456
  float*          tw     = (float*)(wsb + 31457280);            // 16384
  int*            ti     = (int*)(wsb + 31473664);              // 16384
  int*            cnt    = (int*)(wsb + 31490048);              // 256
  int*            lists  = (int*)(wsb + 31490304);              // 65536
  int*            slot   = (int*)(wsb + 31555840);              // 16384
  unsigned short* emb_bf = (unsigned short*)(wsb + 31572224);   // 49152000
  unsigned short* wbf    = (unsigned short*)(wsb + 80724224);   // 61341696 (one layer)
  unsigned short* hg     = (unsigned short*)(wsb + 142065920);  // 50331648
  unsigned short* hu     = (unsigned short*)(wsb + 142065920 + 50331648);
  float*          ye     = (float*)(wsb + 142065920 + 50331648); // overlaps hu

  // per-layer weight staging (producer->consumer cache locality — protected
  // property: upfront conversion churns the LLC and regresses ~35 µs)
  unsigned short* qw_bf = wbf;                 // 1769472
  unsigned short* ow_bf = wbf + 1769472;       // 589824
  unsigned short* eg_bf = wbf + 2359296;       // 9437184 (eu = +8*FF*DM follows)
  unsigned short* ed_bf = wbf + 21233664;      // 9437184

  conv_k<<<12000, 256, 0, stream>>>(emb, emb_bf);
  embed_k<<<SQ * DM / 256, 256, 0, stream>>>(tokens, emb, x_f, x_bf, cnt);

  for (int l = 0; l < NL; ++l) {
    const float* qw = qkv_w + (size_t)l * 3 * DM * DM;
    const float* qb = qkv_b + (size_t)l * 3 * DM;
    const float* ow = out_w + (size_t)l * DM * DM;
    const float* ob = out_b + (size_t)l * DM;
    const float* gw = gate_w + (size_t)l * NE * DM;
    const float* egw = eg_w + (size_t)l * NE * FF * DM;
    const float* euw = eu_w + (size_t)l * NE * FF * DM;
    const float* edw = ed_w + (size_t)l * NE * DM * FF;

    // all 5 weight regions for this layer in ONE dispatch (dest contiguous)
    conv5_k<<<14976, 256, 0, stream>>>(qw, ow, egw, euw, edw, qw_bf);

    // qkv = x @ qkv_w^T + b -> bf16; V cols also written transposed to vt
    gemm_k<false, true, true, true><<<16 * 18, 256, 0, stream>>>(
        x_bf, DM, 0, qw_bf, DM, 0, qb, qkv_bf, 3 * DM, 0,
        SQ, 3 * DM, DM, 1.f, nullptr, 0, nullptr, 16, 18, 1, vt);

    // fused flash attention -> o_bf
    flash_k<<<NHD * 64, 128, 0, stream>>>(qkv_bf, vt, o_bf);

    // attn out-proj -> tmp_f (fp32)
    gemm_k<false, true, false, false><<<16 * 6, 256, 0, stream>>>(
        o_bf, DM, 0, ow_bf, DM, 0, ob, tmp_f, DM, 0,
        SQ, DM, DM, 1.f, nullptr, 0, nullptr, 16, 6, 1, nullptr);

    add_ln_gate_k<<<SQ, 256, 0, stream>>>(x_f, tmp_f, ln1_w + l * DM,
        ln1_b + l * DM, gw, x_f, x_bf, tw, ti, cnt, lists, slot);

    // eg + eu in ONE pipelined dispatch: Z=16 (z<8 gate, z>=8 up)
    gemm256_k<true, true><<<16 * 6 * 16, 512, 0, stream>>>(
        x_bf, DM, eg_bf, DM, (long long)FF * DM,
        hg, FF, (long long)SQ * FF,
        SQ, DM, 16, 6, 16, 8, lists, SQ, cnt);

    silu_mul_k<<<dim3(SQ, NE), 256, 0, stream>>>(hg, hu, cnt);

    // ye = hh @ ed^T (fp32 out), m97 engine: Z=8, full-chip grid
    gemm_k<false, false, false, false><<<16 * 6 * NE, 256, 0, stream>>>(
        hg, FF, (long long)SQ * FF, ed_bf, FF, (long long)DM * FF, nullptr,
        ye, DM, (long long)SQ * DM,
        SQ, DM, FF, 1.f, nullptr, 0, cnt, 16, 6, NE, nullptr);

    if (l == NL - 1)
      combine_ln_k<true><<<SQ, 256, 0, stream>>>(x_f, ye, tw, ti, slot,
          ln2_w + l * DM, ln2_b + l * DM, rms_w, x_f, x_bf, cnt);
    else
      combine_ln_k<false><<<SQ, 256, 0, stream>>>(x_f, ye, tw, ti, slot,
          ln2_w + l * DM, ln2_b + l * DM, rms_w, x_f, x_bf, cnt);
  }

  // logits = xn @ emb_bf^T (fp32) -- 8-wave counted-vmcnt ring engine
  gemmr_k<<<8 * 125, 512, 0, stream>>>(
      x_bf, DM, emb_bf, DM, out, NV, DM, 8);
}

// Round 16
// 761.351 us; speedup vs baseline: 1.0472x; 1.0179x over previous
//
#include <hip/hip_runtime.h>

// ---- problem dims ----
#define SQ   2048
#define DM   768
#define NHD  12
#define DHD  64
#define FF   1536
#define NE   8
#define NL   2
#define NV   32000

typedef __attribute__((ext_vector_type(8))) short bf16x8;
typedef __attribute__((ext_vector_type(4))) float f32x4;

__device__ __forceinline__ unsigned short f2bf(float f) {
  unsigned u = __float_as_uint(f);
  return (unsigned short)((u + 0x7fffu + ((u >> 16) & 1u)) >> 16);
}
__device__ __forceinline__ float bf2f(unsigned short h) {
  return __uint_as_float(((unsigned)h) << 16);
}

// async global->LDS, 16B per lane; dest = wave-uniform base + lane*16
#define GLD16(ldsp, gp) __builtin_amdgcn_global_load_lds( \
    (const __attribute__((address_space(1))) void*)(gp),  \
    (__attribute__((address_space(3))) void*)(ldsp), 16, 0, 0)

__device__ __forceinline__ void conv8(const float* s, unsigned short* d) {
  float4 a = *(const float4*)s;
  float4 b = *(const float4*)(s + 4);
  int4 pk = make_int4(
      (int)((unsigned)f2bf(a.x) | ((unsigned)f2bf(a.y) << 16)),
      (int)((unsigned)f2bf(a.z) | ((unsigned)f2bf(a.w) << 16)),
      (int)((unsigned)f2bf(b.x) | ((unsigned)f2bf(b.y) << 16)),
      (int)((unsigned)f2bf(b.z) | ((unsigned)f2bf(b.w) << 16)));
  *(int4*)d = pk;
}

// ---- fused: emb fp32->bf16 (blocks 0..11999) + embedding (12000..18143) ----
__global__ __launch_bounds__(256) void conv_embed_k(const int* __restrict__ tok,
    const float* __restrict__ emb, unsigned short* __restrict__ emb_bf,
    float* __restrict__ x, unsigned short* __restrict__ xbf,
    int* __restrict__ cnt) {
  int b = blockIdx.x;
  if (b < 12000) {
    size_t i = (size_t)(b * 256 + threadIdx.x) * 8;
    conv8(emb + i, emb_bf + i);
  } else {
    if (b == 12000 && threadIdx.x < NE) cnt[threadIdx.x] = 0;
    int idx = (b - 12000) * 256 + threadIdx.x;   // < 2048*768
    int s = idx / DM, d = idx % DM;
    float v = emb[(size_t)tok[s] * DM + d] * 27.712812921102035f;
    x[idx] = v;
    xbf[idx] = f2bf(v);
  }
}

// 5 regions (qw 864, ow 288, eg 4608, eu 4608, ed 4608), contiguous dest
__global__ __launch_bounds__(256) void conv5_k(const float* __restrict__ s0,
    const float* __restrict__ s1, const float* __restrict__ s2,
    const float* __restrict__ s3, const float* __restrict__ s4,
    unsigned short* __restrict__ d) {
  int b = blockIdx.x;
  const float* s; int sb;
  if (b < 864)        { s = s0; sb = b; }
  else if (b < 1152)  { s = s1; sb = b - 864; }
  else if (b < 5760)  { s = s2; sb = b - 1152; }
  else if (b < 10368) { s = s3; sb = b - 5760; }
  else                { s = s4; sb = b - 10368; }
  size_t di = (size_t)b * 2048 + threadIdx.x * 8;
  size_t si = (size_t)sb * 2048 + threadIdx.x * 8;
  conv8(s + si, d + di);
}

// ============ 256x256 counted-vmcnt ring GEMM (logits engine) ============
// BM=BN=256, 512 thr = 8 waves (2M x 4N), wave tile 128x64.
// LDS = 4 ring slots of K=32 sub-tiles (128 KB). Phase s: {12 ds_read(s) |
// stage(s+2): 4 GLD | lgkm0 | 32 MFMA | vmcnt(4) | barrier}. Swizzle:
// LDS[r][c] = g[r][c ^ ((r>>1)&3)] -> conflict-free b128 lane groups.
__global__ __launch_bounds__(512, 1) void gemmr_k(
    const unsigned short* __restrict__ A, long long lda,
    const unsigned short* __restrict__ B, long long ldb,
    float* __restrict__ C, long long ldc,
    int Kd, int mT)
{
  int nwg = gridDim.x, bid = blockIdx.x;
  int q = nwg >> 3, r = nwg & 7;
  int xcd = bid & 7, j = bid >> 3;
  int wid = (xcd < r ? xcd * (q + 1) : r * (q + 1) + (xcd - r) * q) + j;
  int mt = wid % mT, nt = wid / mT;     // m-fastest: B-panel reuse in XCD L2
  int m0 = mt * 256, n0 = nt * 256;

  __shared__ __align__(16) unsigned short lds[4][2][8192];

  int t = threadIdx.x, w = t >> 6, lane = t & 63;
  int wm = w >> 2, wn = w & 3;
  int fr = lane & 15, ksg = lane >> 4;

  int srow = t >> 2;                    // 0..127
  int schunk = ((t & 3) ^ ((srow >> 1) & 3)) * 8;
  const unsigned short* sa0 = A + (size_t)(m0 +       srow) * lda + schunk;
  const unsigned short* sa1 = A + (size_t)(m0 + 128 + srow) * lda + schunk;
  const unsigned short* sb0 = B + (size_t)(n0 +       srow) * ldb + schunk;
  const unsigned short* sb1 = B + (size_t)(n0 + 128 + srow) * ldb + schunk;
  int wofs = w * 512;

  int NS = Kd >> 5;
  f32x4 acc[8][4] = {};

#define STAGEV(s) { \
    int sl_ = (s) & 3; \
    long long ko_ = (long long)((s) >> 1) * 64 + ((s) & 1) * 32; \
    GLD16(&lds[sl_][0][wofs], sa0 + ko_); \
    GLD16(&lds[sl_][0][4096 + wofs], sa1 + ko_); \
    GLD16(&lds[sl_][1][wofs], sb0 + ko_); \
    GLD16(&lds[sl_][1][4096 + wofs], sb1 + ko_); }

  STAGEV(0);
  STAGEV(1);
  asm volatile("s_waitcnt vmcnt(4)" ::: "memory");
  __builtin_amdgcn_s_barrier();
  __builtin_amdgcn_sched_barrier(0);

  int ko = (ksg ^ ((fr >> 1) & 3)) * 8;
  for (int s = 0; s < NS; ++s) {
    int slot = s & 3;
    const unsigned short* Al = &lds[slot][0][0];
    const unsigned short* Bl = &lds[slot][1][0];
    bf16x8 af[8], bf[4];
    #pragma unroll
    for (int m = 0; m < 8; ++m)
      af[m] = *(const bf16x8*)&Al[(wm * 128 + m * 16 + fr) * 32 + ko];
    #pragma unroll
    for (int n = 0; n < 4; ++n)
      bf[n] = *(const bf16x8*)&Bl[(wn * 64 + n * 16 + fr) * 32 + ko];
    if (s + 2 < NS) STAGEV(s + 2);
    asm volatile("s_waitcnt lgkmcnt(0)" ::: "memory");
    __builtin_amdgcn_sched_barrier(0);
    __builtin_amdgcn_s_setprio(1);
    #pragma unroll
    for (int m = 0; m < 8; ++m)
      #pragma unroll
      for (int n = 0; n < 4; ++n)
        acc[m][n] = __builtin_amdgcn_mfma_f32_16x16x32_bf16(
            af[m], bf[n], acc[m][n], 0, 0, 0);
    __builtin_amdgcn_s_setprio(0);
    if (s + 1 < NS) {
      if (s + 2 < NS) asm volatile("s_waitcnt vmcnt(4)" ::: "memory");
      else            asm volatile("s_waitcnt vmcnt(0)" ::: "memory");
      __builtin_amdgcn_s_barrier();
      __builtin_amdgcn_sched_barrier(0);
    }
  }
#undef STAGEV

  int rb = ksg * 4;
  #pragma unroll
  for (int M = 0; M < 8; ++M)
    #pragma unroll
    for (int n = 0; n < 4; ++n)
      #pragma unroll
      for (int rr = 0; rr < 4; ++rr)
        C[(size_t)(m0 + wm * 128 + M * 16 + rb + rr) * ldc +
          (n0 + wn * 64 + n * 16 + fr)] = acc[M][n][rr];
}

// ======== pipelined 128x256 GEMM engine (Z/gather; used for eg+eu) ========
template<bool GATHER, bool OBF16>
__global__ __launch_bounds__(512) void gemm256_k(
    const unsigned short* __restrict__ A, long long lda,
    const unsigned short* __restrict__ B, long long ldb, long long b_z,
    void* __restrict__ C, long long ldc, long long c_z,
    int M, int Kd, int mT, int nT, int Z, int zmod,
    const int* __restrict__ glist, long long gl_z,
    const int* __restrict__ cnt)
{
  int nwg = gridDim.x, bid = blockIdx.x;
  int q = nwg >> 3, r = nwg & 7;
  int xcd = bid & 7, j = bid >> 3;
  int wid = (xcd < r ? xcd * (q + 1) : r * (q + 1) + (xcd - r) * q) + j;
  int z = wid % Z; int rem = wid / Z;
  int mt = rem % mT, nt = rem / mT;
  int zz = z % zmod;
  int Mz = cnt ? cnt[zz] : M;
  int m0 = mt * 128, n0 = nt * 256;
  if (m0 >= Mz) return;
  (void)nT;

  const unsigned short* Bz = B + (size_t)z * b_z;

  __shared__ __align__(16) unsigned short lds[3 * 6 * 4096];

  int t = threadIdx.x, w = t >> 6, lane = t & 63;
  int wm = (w >> 2) * 64, wn = (w & 3) * 64;
  int fr = lane & 15, ksg = lane >> 4;
  int lrow = lane >> 3;
  int lchunk = ((lane & 7) ^ lrow) * 8;

  const unsigned short* sp[6];
  #pragma unroll
  for (int hh = 0; hh < 2; ++hh) {
    int gr = m0 + hh * 64 + w * 8 + lrow; if (gr >= Mz) gr = Mz - 1;
    int arow;
    if constexpr (GATHER) arow = glist[(size_t)zz * gl_z + gr]; else arow = gr;
    sp[hh] = A + (size_t)arow * lda + lchunk;
  }
  #pragma unroll
  for (int hh = 0; hh < 4; ++hh)
    sp[2 + hh] = Bz + (size_t)(n0 + hh * 64 + w * 8 + lrow) * ldb + lchunk;

  int rdA = (w >> 2) * 4096;
  int rdB = (2 + (w & 3)) * 4096;
  int stDst = w * 512;

  int rx = fr & 7;
  int off0 = (ksg ^ rx) * 8;
  int off1 = ((4 + ksg) ^ rx) * 8;

  int KT = Kd >> 6;
  f32x4 acc[4][4] = {};

  #pragma unroll
  for (int h = 0; h < 6; ++h)
    GLD16(&lds[h * 4096 + stDst], sp[h]);
  #pragma unroll
  for (int h = 0; h < 6; ++h)
    GLD16(&lds[(6 + h) * 4096 + stDst], sp[h] + 64);
  asm volatile("s_waitcnt vmcnt(6)" ::: "memory");
  __builtin_amdgcn_s_barrier();
  __builtin_amdgcn_sched_barrier(0);

  int buf = 0;
  for (int kt = 0; kt < KT; ++kt) {
    const unsigned short* Abl = &lds[buf * 6 * 4096 + rdA];
    const unsigned short* Bbl = &lds[buf * 6 * 4096 + rdB];
    int pf = (kt + 2 < KT);
    int pbuf = buf + 2; if (pbuf >= 3) pbuf -= 3;
    unsigned short* pd = &lds[pbuf * 6 * 4096 + stDst];
    long long koff = (long long)(kt + 2) * 64;

    if (pf) {
      GLD16(pd + 0 * 4096, sp[0] + koff);
      GLD16(pd + 1 * 4096, sp[1] + koff);
      GLD16(pd + 2 * 4096, sp[2] + koff);
    }
    {
      bf16x8 af[4], bv[4];
      #pragma unroll
      for (int m = 0; m < 4; ++m)
        af[m] = *(const bf16x8*)&Abl[(m * 16 + fr) * 64 + off0];
      #pragma unroll
      for (int n = 0; n < 4; ++n)
        bv[n] = *(const bf16x8*)&Bbl[(n * 16 + fr) * 64 + off0];
      __builtin_amdgcn_s_setprio(1);
      #pragma unroll
      for (int m = 0; m < 4; ++m)
        #pragma unroll
        for (int n = 0; n < 4; ++n)
          acc[m][n] = __builtin_amdgcn_mfma_f32_16x16x32_bf16(
              af[m], bv[n], acc[m][n], 0, 0, 0);
      __builtin_amdgcn_s_setprio(0);
    }
    if (pf) {
      GLD16(pd + 3 * 4096, sp[3] + koff);
      GLD16(pd + 4 * 4096, sp[4] + koff);
      GLD16(pd + 5 * 4096, sp[5] + koff);
    }
    {
      bf16x8 af[4], bv[4];
      #pragma unroll
      for (int m = 0; m < 4; ++m)
        af[m] = *(const bf16x8*)&Abl[(m * 16 + fr) * 64 + off1];
      #pragma unroll
      for (int n = 0; n < 4; ++n)
        bv[n] = *(const bf16x8*)&Bbl[(n * 16 + fr) * 64 + off1];
      __builtin_amdgcn_s_setprio(1);
      #pragma unroll
      for (int m = 0; m < 4; ++m)
        #pragma unroll
        for (int n = 0; n < 4; ++n)
          acc[m][n] = __builtin_amdgcn_mfma_f32_16x16x32_bf16(
              af[m], bv[n], acc[m][n], 0, 0, 0);
      __builtin_amdgcn_s_setprio(0);
    }
    if (pf) {
      asm volatile("s_waitcnt vmcnt(6)" ::: "memory");
    } else if (kt + 1 < KT) {
      asm volatile("s_waitcnt vmcnt(0)" ::: "memory");
    }
    __builtin_amdgcn_s_barrier();
    __builtin_amdgcn_sched_barrier(0);
    buf = buf + 1; if (buf == 3) buf = 0;
  }

  int rb = ksg * 4;
  #pragma unroll
  for (int m = 0; m < 4; ++m) {
    #pragma unroll
    for (int n = 0; n < 4; ++n) {
      #pragma unroll
      for (int rr = 0; rr < 4; ++rr) {
        int row = m0 + wm + m * 16 + rb + rr;
        if (row >= Mz) continue;
        size_t off = (size_t)z * c_z + (size_t)row * ldc +
                     (n0 + wn + n * 16 + fr);
        if constexpr (OBF16) ((unsigned short*)C)[off] = f2bf(acc[m][n][rr]);
        else                 ((float*)C)[off] = acc[m][n][rr];
      }
    }
  }
}

// ---------------- bf16 MFMA GEMM, m97 structure (+optional V-transpose) ----
template<bool GATHER, bool BIAS, bool OBF16, bool VT>
__global__ __launch_bounds__(256) void gemm_k(
    const unsigned short* __restrict__ A, long long lda, long long a_z,
    const unsigned short* __restrict__ B, long long ldb, long long b_z,
    const float* __restrict__ bias,
    void* __restrict__ C, long long ldc, long long c_z,
    int M, int N, int Kd, float scale,
    const int* __restrict__ glist, long long gl_z,
    const int* __restrict__ cnt, int mT, int nT, int Z,
    unsigned short* __restrict__ vtout)
{
  int nwg = gridDim.x, bid = blockIdx.x;
  int q = nwg >> 3, r = nwg & 7;
  int xcd = bid & 7, j = bid >> 3;
  int wid = (xcd < r ? xcd * (q + 1) : r * (q + 1) + (xcd - r) * q) + j;
  int z = wid % Z; int rem = wid / Z;
  int mt = rem % mT, nt = rem / mT;

  int Mz = cnt ? cnt[z] : M;
  int m0 = mt * 128, n0 = nt * 128;
  if (m0 >= Mz) return;

  const unsigned short* Ab = A + (size_t)z * a_z;
  const unsigned short* Bb = B + (size_t)z * b_z;

  __shared__ __align__(16) unsigned short As[128 * 64];
  __shared__ __align__(16) unsigned short Bs[128 * 64];

  int t = threadIdx.x, w = t >> 6, lane = t & 63;
  int wm = (w >> 1) * 64, wn = (w & 1) * 64;
  int fr = lane & 15, ksg = lane >> 4;
  int lrow = lane >> 3;
  int lchunk = ((lane & 7) ^ lrow) * 8;

  const unsigned short* ap[4];
  const unsigned short* bp[4];
  unsigned short* la[4];
  unsigned short* lb[4];
  #pragma unroll
  for (int i = 0; i < 4; ++i) {
    int rrow = w * 32 + i * 8 + lrow;
    int gr = m0 + rrow; if (gr >= Mz) gr = Mz - 1;
    int arow; if constexpr (GATHER) arow = glist[(size_t)z * gl_z + gr]; else arow = gr;
    ap[i] = Ab + (size_t)arow * lda + lchunk;
    int br = n0 + rrow; if (br >= N) br = N - 1;
    bp[i] = Bb + (size_t)br * ldb + lchunk;
    la[i] = &As[(w * 32 + i * 8) * 64];
    lb[i] = &Bs[(w * 32 + i * 8) * 64];
  }

  int rx = fr & 7;
  int off0 = ((0 + ksg) ^ rx) * 8;
  int off1 = ((4 + ksg) ^ rx) * 8;

  f32x4 acc[4][4] = {};

  for (int k0 = 0; k0 < Kd; k0 += 64) {
    #pragma unroll
    for (int i = 0; i < 4; ++i) GLD16(la[i], ap[i] + k0);
    #pragma unroll
    for (int i = 0; i < 4; ++i) GLD16(lb[i], bp[i] + k0);
    __syncthreads();
    #pragma unroll
    for (int kb = 0; kb < 2; ++kb) {
      int offk = kb ? off1 : off0;
      bf16x8 af[4], bv[4];
      #pragma unroll
      for (int m = 0; m < 4; ++m)
        af[m] = *(const bf16x8*)&As[(wm + m * 16 + fr) * 64 + offk];
      #pragma unroll
      for (int n = 0; n < 4; ++n)
        bv[n] = *(const bf16x8*)&Bs[(wn + n * 16 + fr) * 64 + offk];
      #pragma unroll
      for (int m = 0; m < 4; ++m)
        #pragma unroll
        for (int n = 0; n < 4; ++n)
          acc[m][n] = __builtin_amdgcn_mfma_f32_16x16x32_bf16(
              af[m], bv[n], acc[m][n], 0, 0, 0);
    }
    __syncthreads();
  }

  int rb = ksg * 4;
  #pragma unroll
  for (int m = 0; m < 4; ++m) {
    #pragma unroll
    for (int n = 0; n < 4; ++n) {
      int col = n0 + wn + n * 16 + fr;
      if (col >= N) continue;
      #pragma unroll
      for (int rr = 0; rr < 4; ++rr) {
        int row = m0 + wm + m * 16 + rb + rr;
        if (row >= Mz) continue;
        float v = acc[m][n][rr] * scale;
        if constexpr (BIAS) v += bias[col];
        size_t off = (size_t)z * c_z + (size_t)row * ldc + col;
        if constexpr (OBF16) ((unsigned short*)C)[off] = f2bf(v);
        else                 ((float*)C)[off] = v;
        if constexpr (VT) {
          if (n0 >= 2 * DM)   // whole block in V range (block-uniform)
            vtout[(size_t)(col - 2 * DM) * SQ + row] = f2bf(v);
        }
      }
    }
  }
}

// ---------------- flash attention (2-wave blocks, 32 q-rows) ----------------
__global__ __launch_bounds__(128) void flash_k(
    const unsigned short* __restrict__ qkv,   // [SQ][3*DM] bf16
    const unsigned short* __restrict__ vt,    // [NHD*DHD][SQ] bf16 (V^T)
    unsigned short* __restrict__ o)           // [SQ][DM] bf16
{
  int nwg = gridDim.x, bid = blockIdx.x;      // nwg = 768
  int cpx = nwg >> 3;
  int wid = (bid & 7) * cpx + (bid >> 3);
  int h  = wid >> 6;
  int qt = wid & 63;
  int q0 = qt * 32;

  __shared__ __align__(16) unsigned short Ks[128 * 64];
  __shared__ __align__(16) unsigned short Vs[128 * 64];
  __shared__ __align__(16) unsigned short Ps[2][16 * 136];

  int t = threadIdx.x, w = t >> 6, lane = t & 63;
  int fr = lane & 15, ksg = lane >> 4;
  int lrow = lane >> 3;
  int lchunk = ((lane & 7) ^ lrow) * 8;

  const unsigned short* qbase = qkv + (size_t)q0 * (3 * DM) + h * DHD;
  #pragma unroll
  for (int i = 0; i < 2; ++i) {
    int rrow = w * 16 + i * 8 + lrow;
    GLD16(&Ks[(w * 16 + i * 8) * 64], qbase + (size_t)rrow * (3 * DM) + lchunk);
  }
  __syncthreads();
  bf16x8 qf[2];
  {
    int row = w * 16 + fr, ph = fr & 7;
    qf[0] = *(const bf16x8*)&Ks[row * 64 + ((ksg ^ ph) * 8)];
    qf[1] = *(const bf16x8*)&Ks[row * 64 + (((4 + ksg) ^ ph) * 8)];
  }
  __syncthreads();

  const unsigned short* kbase = qkv + DM + h * DHD;
  const unsigned short* vb = vt + (size_t)(h * DHD) * SQ;

  f32x4 oacc[4] = {};
  float m_r[4] = {-1e30f, -1e30f, -1e30f, -1e30f};
  float l_r[4] = {0.f, 0.f, 0.f, 0.f};

  for (int kt = 0; kt < SQ / 128; ++kt) {
    int kk0 = kt * 128;
    #pragma unroll
    for (int i = 0; i < 8; ++i) {
      int rrow = w * 64 + i * 8 + lrow;
      GLD16(&Ks[(w * 64 + i * 8) * 64],
            kbase + (size_t)(kk0 + rrow) * (3 * DM) + lchunk);
    }
    #pragma unroll
    for (int i = 0; i < 8; ++i) {
      int p = w * 64 + i * 8 + lrow;
      GLD16(&Vs[(w * 64 + i * 8) * 64],
            vb + (size_t)(p >> 1) * SQ + kk0 + (p & 1) * 64 + lchunk);
    }
    __syncthreads();

    f32x4 sacc[8] = {};
    __builtin_amdgcn_s_setprio(1);
    #pragma unroll
    for (int kb = 0; kb < 2; ++kb) {
      #pragma unroll
      for (int n = 0; n < 8; ++n) {
        int row = n * 16 + fr;
        bf16x8 bvv = *(const bf16x8*)&Ks[row * 64 +
            (((kb * 4 + ksg) ^ (fr & 7)) * 8)];
        sacc[n] = __builtin_amdgcn_mfma_f32_16x16x32_bf16(
            qf[kb], bvv, sacc[n], 0, 0, 0);
      }
    }
    __builtin_amdgcn_s_setprio(0);

    #pragma unroll
    for (int r = 0; r < 4; ++r) {
      float mx = sacc[0][r];
      #pragma unroll
      for (int n = 1; n < 8; ++n) mx = fmaxf(mx, sacc[n][r]);
      mx = fmaxf(mx, __shfl_xor(mx, 1));
      mx = fmaxf(mx, __shfl_xor(mx, 2));
      mx = fmaxf(mx, __shfl_xor(mx, 4));
      mx = fmaxf(mx, __shfl_xor(mx, 8));
      float mn = fmaxf(m_r[r], mx * 0.125f);
      float resc = __expf(m_r[r] - mn);
      m_r[r] = mn;
      #pragma unroll
      for (int n = 0; n < 4; ++n) oacc[n][r] *= resc;
      float rs = 0.f;
      #pragma unroll
      for (int n = 0; n < 8; ++n) {
        float p = __expf(sacc[n][r] * 0.125f - mn);
        rs += p;
        Ps[w][(ksg * 4 + r) * 136 + n * 16 + fr] = f2bf(p);
      }
      rs += __shfl_xor(rs, 1);
      rs += __shfl_xor(rs, 2);
      rs += __shfl_xor(rs, 4);
      rs += __shfl_xor(rs, 8);
      l_r[r] = l_r[r] * resc + rs;
    }

    __builtin_amdgcn_s_setprio(1);
    #pragma unroll
    for (int ksi = 0; ksi < 4; ++ksi) {
      bf16x8 pa = *(const bf16x8*)&Ps[w][fr * 136 + ksi * 32 + ksg * 8];
      #pragma unroll
      for (int n = 0; n < 4; ++n) {
        int p = (n * 16 + fr) * 2 + (ksi >> 1);
        int c = (ksi & 1) * 4 + ksg;
        bf16x8 bvv = *(const bf16x8*)&Vs[p * 64 + ((c ^ (p & 7)) * 8)];
        oacc[n] = __builtin_amdgcn_mfma_f32_16x16x32_bf16(
            pa, bvv, oacc[n], 0, 0, 0);
      }
    }
    __builtin_amdgcn_s_setprio(0);
    __syncthreads();
  }

  unsigned short* ob = o + (size_t)(q0 + w * 16) * DM + h * DHD;
  #pragma unroll
  for (int r = 0; r < 4; ++r) {
    float invl = 1.f / l_r[r];
    int qrow = ksg * 4 + r;
    #pragma unroll
    for (int n = 0; n < 4; ++n)
      ob[(size_t)qrow * DM + n * 16 + fr] = f2bf(oacc[n][r] * invl);
  }
}

// ---------------- x = LN(x + add) + fused MoE gate/top-2 ----------------
__global__ __launch_bounds__(256) void add_ln_gate_k(const float* __restrict__ xin,
    const float* __restrict__ add, const float* __restrict__ w,
    const float* __restrict__ b, const float* __restrict__ gw,
    float* __restrict__ xout, unsigned short* __restrict__ xbf,
    float* __restrict__ tw, int* __restrict__ ti, int* __restrict__ cnt,
    int* __restrict__ lists, int* __restrict__ slot) {
  int row = blockIdx.x, t = threadIdx.x;
  const float* xi = xin + (size_t)row * DM;
  const float* ai = add + (size_t)row * DM;
  float v[3]; float s = 0.f, sq = 0.f;
  #pragma unroll
  for (int i = 0; i < 3; ++i) {
    int idx = t + i * 256;
    v[i] = xi[idx] + ai[idx];
    s += v[i]; sq += v[i] * v[i];
  }
  #pragma unroll
  for (int o = 32; o; o >>= 1) { s += __shfl_xor(s, o); sq += __shfl_xor(sq, o); }
  __shared__ float rsm[4], rqm[4];
  __shared__ float gsm[4][NE];
  int wv = t >> 6, lane = t & 63;
  if (lane == 0) { rsm[wv] = s; rqm[wv] = sq; }
  __syncthreads();
  s = rsm[0] + rsm[1] + rsm[2] + rsm[3];
  sq = rqm[0] + rqm[1] + rqm[2] + rqm[3];
  float mean = s * (1.f / 768.f);
  float var = sq * (1.f / 768.f) - mean * mean;
  float inv = rsqrtf(var + 1e-5f);
  float* xo = xout + (size_t)row * DM;
  unsigned short* xb = xbf + (size_t)row * DM;
  float y[3];
  #pragma unroll
  for (int i = 0; i < 3; ++i) {
    int idx = t + i * 256;
    y[i] = (v[i] - mean) * inv * w[idx] + b[idx];
    xo[idx] = y[i]; xb[idx] = f2bf(y[i]);
  }
  float p[NE];
  #pragma unroll
  for (int e = 0; e < NE; ++e) {
    p[e] = y[0] * gw[e * DM + t] + y[1] * gw[e * DM + t + 256]
         + y[2] * gw[e * DM + t + 512];
    #pragma unroll
    for (int o = 32; o; o >>= 1) p[e] += __shfl_xor(p[e], o);
  }
  if (lane == 0) {
    #pragma unroll
    for (int e = 0; e < NE; ++e) gsm[wv][e] = p[e];
  }
  __syncthreads();
  if (t == 0) {
    float v0 = -1e30f, v1 = -1e30f; int i0 = 0, i1 = 0;
    #pragma unroll
    for (int e = 0; e < NE; ++e) {
      float g = gsm[0][e] + gsm[1][e] + gsm[2][e] + gsm[3][e];
      if (g > v0) { v1 = v0; i1 = i0; v0 = g; i0 = e; }
      else if (g > v1) { v1 = g; i1 = e; }
    }
    float e1 = expf(v1 - v0);
    float invs = 1.f / (1.f + e1);
    tw[row * 2] = invs; tw[row * 2 + 1] = e1 * invs;
    ti[row * 2] = i0;   ti[row * 2 + 1] = i1;
    int p0 = atomicAdd(&cnt[i0], 1); lists[i0 * SQ + p0] = row; slot[row * 2] = p0;
    int p1 = atomicAdd(&cnt[i1], 1); lists[i1 * SQ + p1] = row; slot[row * 2 + 1] = p1;
  }
}

// ---------------- hh = silu(hg) * hu (in-place into hg) ----------------
__global__ __launch_bounds__(256) void silu_mul_k(unsigned short* __restrict__ hg,
    const unsigned short* __restrict__ hu, const int* __restrict__ cnt) {
  int e = blockIdx.y, sl = blockIdx.x;
  if (sl >= cnt[e]) return;
  size_t base = ((size_t)e * SQ + sl) * FF;
  int t = threadIdx.x;
  #pragma unroll
  for (int i = 0; i < FF / 256; ++i) {
    size_t idx = base + t + i * 256;
    float g = bf2f(hg[idx]);
    float u = bf2f(hu[idx]);
    float sv = g / (1.f + expf(-g));
    hg[idx] = f2bf(sv * u);
  }
}

// ---------------- moe combine + LN (+optional fused final RMSNorm) --------
template<bool FINAL>
__global__ __launch_bounds__(256) void combine_ln_k(const float* __restrict__ xin,
    const float* __restrict__ ye, const float* __restrict__ tw,
    const int* __restrict__ ti, const int* __restrict__ slot,
    const float* __restrict__ w, const float* __restrict__ b,
    const float* __restrict__ rw,
    float* __restrict__ xout, unsigned short* __restrict__ xbf,
    int* __restrict__ cnt) {
  int row = blockIdx.x, t = threadIdx.x;
  if (!FINAL && row < NE && t == 0) cnt[row] = 0;
  int e0 = ti[row * 2], e1 = ti[row * 2 + 1];
  int p0 = slot[row * 2], p1 = slot[row * 2 + 1];
  float w0 = tw[row * 2], w1 = tw[row * 2 + 1];
  const float* y0 = ye + ((size_t)e0 * SQ + p0) * DM;
  const float* y1 = ye + ((size_t)e1 * SQ + p1) * DM;
  const float* xi = xin + (size_t)row * DM;
  float v[3]; float s = 0.f, sq = 0.f;
  #pragma unroll
  for (int i = 0; i < 3; ++i) {
    int idx = t + i * 256;
    v[i] = xi[idx] + w0 * y0[idx] + w1 * y1[idx];
    s += v[i]; sq += v[i] * v[i];
  }
  #pragma unroll
  for (int o = 32; o; o >>= 1) { s += __shfl_xor(s, o); sq += __shfl_xor(sq, o); }
  __shared__ float rsm[4], rqm[4];
  int wv = t >> 6;
  if ((t & 63) == 0) { rsm[wv] = s; rqm[wv] = sq; }
  __syncthreads();
  s = rsm[0] + rsm[1] + rsm[2] + rsm[3];
  sq = rqm[0] + rqm[1] + rqm[2] + rqm[3];
  float mean = s * (1.f / 768.f);
  float var = sq * (1.f / 768.f) - mean * mean;
  float inv = rsqrtf(var + 1e-5f);
  unsigned short* xb = xbf + (size_t)row * DM;
  float y[3];
  #pragma unroll
  for (int i = 0; i < 3; ++i) {
    int idx = t + i * 256;
    y[i] = (v[i] - mean) * inv * w[idx] + b[idx];
  }
  if constexpr (!FINAL) {
    float* xo = xout + (size_t)row * DM;
    #pragma unroll
    for (int i = 0; i < 3; ++i) {
      int idx = t + i * 256;
      xo[idx] = y[i]; xb[idx] = f2bf(y[i]);
    }
  } else {
    float sq2 = y[0] * y[0] + y[1] * y[1] + y[2] * y[2];
    #pragma unroll
    for (int o = 32; o; o >>= 1) sq2 += __shfl_xor(sq2, o);
    __syncthreads();
    if ((t & 63) == 0) rqm[wv] = sq2;
    __syncthreads();
    sq2 = rqm[0] + rqm[1] + rqm[2] + rqm[3];
    float inv2 = rsqrtf(sq2 * (1.f / 768.f) + 1.1920929e-07f);
    #pragma unroll
    for (int i = 0; i < 3; ++i) {
      int idx = t + i * 256;
      xb[idx] = f2bf(y[i] * inv2 * rw[idx]);
    }
  }
}

// ================= host =================
extern "C" void kernel_launch(void* const* d_in, const int* in_sizes, int n_in,
                              void* d_out, int out_size, void* d_ws, size_t ws_size,
                              hipStream_t stream) {
  (void)in_sizes; (void)n_in; (void)out_size; (void)ws_size;
  const int*   tokens = (const int*)d_in[0];
  const float* emb    = (const float*)d_in[1];
  const float* qkv_w  = (const float*)d_in[2];
  const float* qkv_b  = (const float*)d_in[3];
  const float* out_w  = (const float*)d_in[4];
  const float* out_b  = (const float*)d_in[5];
  const float* ln1_w  = (const float*)d_in[6];
  const float* ln1_b  = (const float*)d_in[7];
  const float* ln2_w  = (const float*)d_in[8];
  const float* ln2_b  = (const float*)d_in[9];
  const float* gate_w = (const float*)d_in[10];
  const float* eg_w   = (const float*)d_in[11];
  const float* eu_w   = (const float*)d_in[12];
  const float* ed_w   = (const float*)d_in[13];
  const float* rms_w  = (const float*)d_in[14];
  float* out = (float*)d_out;

  char* wsb = (char*)d_ws;
  float*          x_f    = (float*)(wsb + 0);                   // 6291456
  unsigned short* x_bf   = (unsigned short*)(wsb + 6291456);    // 3145728
  unsigned short* qkv_bf = (unsigned short*)(wsb + 9437184);    // 9437184
  unsigned short* vt     = (unsigned short*)(wsb + 18874368);   // 3145728
  unsigned short* o_bf   = (unsigned short*)(wsb + 22020096);   // 3145728
  float*          tmp_f  = (float*)(wsb + 25165824);            // 6291456
  float*          tw     = (float*)(wsb + 31457280);            // 16384
  int*            ti     = (int*)(wsb + 31473664);              // 16384
  int*            cnt    = (int*)(wsb + 31490048);              // 256
  int*            lists  = (int*)(wsb + 31490304);              // 65536
  int*            slot   = (int*)(wsb + 31555840);              // 16384
  unsigned short* emb_bf = (unsigned short*)(wsb + 31572224);   // 49152000
  unsigned short* wbf    = (unsigned short*)(wsb + 80724224);   // 61341696 (one layer)
  unsigned short* hg     = (unsigned short*)(wsb + 142065920);  // 50331648
  unsigned short* hu     = (unsigned short*)(wsb + 142065920 + 50331648);
  float*          ye     = (float*)(wsb + 142065920 + 50331648); // overlaps hu

  // per-layer weight staging (producer->consumer cache locality — protected
  // property: upfront conversion churns the LLC and regresses ~35 µs)
  unsigned short* qw_bf = wbf;                 // 1769472
  unsigned short* ow_bf = wbf + 1769472;       // 589824
  unsigned short* eg_bf = wbf + 2359296;       // 9437184 (eu = +8*FF*DM follows)
  unsigned short* ed_bf = wbf + 21233664;      // 9437184

  // emb conversion + embedding + cnt zero in ONE dispatch
  conv_embed_k<<<18144, 256, 0, stream>>>(tokens, emb, emb_bf, x_f, x_bf, cnt);

  for (int l = 0; l < NL; ++l) {
    const float* qw = qkv_w + (size_t)l * 3 * DM * DM;
    const float* qb = qkv_b + (size_t)l * 3 * DM;
    const float* ow = out_w + (size_t)l * DM * DM;
    const float* ob = out_b + (size_t)l * DM;
    const float* gw = gate_w + (size_t)l * NE * DM;
    const float* egw = eg_w + (size_t)l * NE * FF * DM;
    const float* euw = eu_w + (size_t)l * NE * FF * DM;
    const float* edw = ed_w + (size_t)l * NE * DM * FF;

    // all 5 weight regions for this layer in ONE dispatch (dest contiguous)
    conv5_k<<<14976, 256, 0, stream>>>(qw, ow, egw, euw, edw, qw_bf);

    // qkv = x @ qkv_w^T + b -> bf16; V cols also written transposed to vt
    gemm_k<false, true, true, true><<<16 * 18, 256, 0, stream>>>(
        x_bf, DM, 0, qw_bf, DM, 0, qb, qkv_bf, 3 * DM, 0,
        SQ, 3 * DM, DM, 1.f, nullptr, 0, nullptr, 16, 18, 1, vt);

    // fused flash attention -> o_bf
    flash_k<<<NHD * 64, 128, 0, stream>>>(qkv_bf, vt, o_bf);

    // attn out-proj -> tmp_f (fp32)
    gemm_k<false, true, false, false><<<16 * 6, 256, 0, stream>>>(
        o_bf, DM, 0, ow_bf, DM, 0, ob, tmp_f, DM, 0,
        SQ, DM, DM, 1.f, nullptr, 0, nullptr, 16, 6, 1, nullptr);

    add_ln_gate_k<<<SQ, 256, 0, stream>>>(x_f, tmp_f, ln1_w + l * DM,
        ln1_b + l * DM, gw, x_f, x_bf, tw, ti, cnt, lists, slot);

    // eg + eu in ONE pipelined dispatch: Z=16 (z<8 gate, z>=8 up)
    gemm256_k<true, true><<<16 * 6 * 16, 512, 0, stream>>>(
        x_bf, DM, eg_bf, DM, (long long)FF * DM,
        hg, FF, (long long)SQ * FF,
        SQ, DM, 16, 6, 16, 8, lists, SQ, cnt);

    silu_mul_k<<<dim3(SQ, NE), 256, 0, stream>>>(hg, hu, cnt);

    // ye = hh @ ed^T (fp32 out), m97 engine: Z=8, full-chip grid
    gemm_k<false, false, false, false><<<16 * 6 * NE, 256, 0, stream>>>(
        hg, FF, (long long)SQ * FF, ed_bf, FF, (long long)DM * FF, nullptr,
        ye, DM, (long long)SQ * DM,
        SQ, DM, FF, 1.f, nullptr, 0, cnt, 16, 6, NE, nullptr);

    if (l == NL - 1)
      combine_ln_k<true><<<SQ, 256, 0, stream>>>(x_f, ye, tw, ti, slot,
          ln2_w + l * DM, ln2_b + l * DM, rms_w, x_f, x_bf, cnt);
    else
      combine_ln_k<false><<<SQ, 256, 0, stream>>>(x_f, ye, tw, ti, slot,
          ln2_w + l * DM, ln2_b + l * DM, rms_w, x_f, x_bf, cnt);
  }

  // logits = xn @ emb_bf^T (fp32) -- 8-wave counted-vmcnt ring engine
  gemmr_k<<<8 * 125, 512, 0, stream>>>(
      x_bf, DM, emb_bf, DM, out, NV, DM, 8);
}